// Round 14
// baseline (152.717 us; speedup 1.0000x reference)
//
#include <hip/hip_runtime.h>
#include <math.h>

#define BB 8
#define TT 8192
#define XX 64
#define HH 128
#define CHUNK 32
#define NC (TT/CHUNK)

typedef __attribute__((ext_vector_type(8))) short short8;
typedef __attribute__((ext_vector_type(4))) float f32x4;

// fast sigmoid: v_rcp_f32 (~1 ulp) instead of IEEE div sequence.
__device__ __forceinline__ float sigm(float x){
  return __builtin_amdgcn_rcpf(1.0f + __expf(-x));
}
__device__ __forceinline__ unsigned short f2bf(float f){
  unsigned u = __float_as_uint(f);
  return (unsigned short)((u + 0x7fffu + ((u>>16)&1u)) >> 16);
}
__device__ __forceinline__ float bf2f(unsigned b){ return __uint_as_float(b << 16); }

// P0: build bf16 weight tables, pre-swizzled (byte ^= (col&7)<<4).
__global__ __launch_bounds__(256) void prep_kernel(
    const float* __restrict__ w1, const float* __restrict__ w2, const float* __restrict__ w3,
    const float* __restrict__ ew, const float* __restrict__ pw,
    unsigned short* __restrict__ wt, unsigned short* __restrict__ wt_e, unsigned short* __restrict__ wt_p)
{
  int idx = blockIdx.x*256 + threadIdx.x;
  if (idx < 98304) {
    int l = idx >> 15;
    int e = idx & 32767;
    int k = e >> 8;
    int col = e & 255;
    const float* w = (l==0) ? w1 : ((l==1) ? w2 : w3);
    float v = w[e];
    unsigned byte = ((unsigned)col*128u + (unsigned)k)*2u;
    byte ^= (unsigned)((col & 7) << 4);
    wt[(size_t)l*32768 + (byte >> 1)] = f2bf(v);
  } else if (idx < 106496) {
    int e = idx - 98304;
    int col = e >> 6, k = e & 63;
    float v = ew[k*HH + col];
    unsigned byte = ((unsigned)e*2u) ^ (unsigned)((col & 7) << 4);
    wt_e[byte >> 1] = f2bf(v);
  } else if (idx < 114688) {
    int e = idx - 106496;
    int col = e >> 7, k = e & 127;
    float v = (col < 50) ? pw[k*50 + col] : 0.f;
    unsigned byte = ((unsigned)e*2u) ^ (unsigned)((col & 7) << 4);
    wt_p[byte >> 1] = f2bf(v);
  }
}

// K1: embed (64->128) MFMA + leaky_relu + LN0 -> h (bf16)   [green text]
__global__ __launch_bounds__(256) void embed_mfma_kernel(
    const float* __restrict__ x, const unsigned short* __restrict__ wt_e,
    const float* __restrict__ eb, const float* __restrict__ g, const float* __restrict__ be,
    unsigned short* __restrict__ hout)
{
  __shared__ short8 wlds[1024];
  int tid = threadIdx.x;
  const short8* wsrc = (const short8*)wt_e;
  #pragma unroll
  for (int i = 0; i < 4; ++i) wlds[i*256 + tid] = wsrc[i*256 + tid];

  int wid = tid >> 6, lane = tid & 63;
  int lr = lane & 15, lg = lane >> 4;
  int sx = (lane & 7) << 4;
  long row0 = (long)(blockIdx.x*4 + wid)*32;

  short8 af[2][2];
  #pragma unroll
  for (int m = 0; m < 2; ++m)
    #pragma unroll
    for (int s = 0; s < 2; ++s) {
      const float* xp = x + (row0 + m*16 + lr)*XX + s*32 + lg*8;
      float4 u0 = *(const float4*)xp;
      float4 u1 = *(const float4*)(xp + 4);
      short8 t;
      t[0]=f2bf(u0.x); t[1]=f2bf(u0.y); t[2]=f2bf(u0.z); t[3]=f2bf(u0.w);
      t[4]=f2bf(u1.x); t[5]=f2bf(u1.y); t[6]=f2bf(u1.z); t[7]=f2bf(u1.w);
      af[m][s] = t;
    }
  __syncthreads();

  const char* wbase = (const char*)wlds;
  f32x4 acc[2][8];
  #pragma unroll
  for (int m = 0; m < 2; ++m)
    #pragma unroll
    for (int np = 0; np < 8; ++np) acc[m][np] = (f32x4){0.f,0.f,0.f,0.f};

  #pragma unroll
  for (int np = 0; np < 8; ++np) {
    int col = np*16 + lr;
    #pragma unroll
    for (int s = 0; s < 2; ++s) {
      short8 bh = *(const short8*)(wbase + ((col*128 + s*64 + lg*16) ^ sx));
      #pragma unroll
      for (int m = 0; m < 2; ++m)
        acc[m][np] = __builtin_amdgcn_mfma_f32_16x16x32_bf16(af[m][s], bh, acc[m][np], 0, 0, 0);
    }
  }

  float gamv[8], betv[8], biasv[8];
  #pragma unroll
  for (int np = 0; np < 8; ++np) {
    int col = np*16 + lr;
    gamv[np] = g[col]; betv[np] = be[col]; biasv[np] = eb[col];
  }

  #pragma unroll
  for (int m = 0; m < 2; ++m) {
    float s4[4], q4[4];
    #pragma unroll
    for (int r = 0; r < 4; ++r) { s4[r] = 0.f; q4[r] = 0.f; }
    #pragma unroll
    for (int np = 0; np < 8; ++np)
      #pragma unroll
      for (int r = 0; r < 4; ++r) {
        float v = acc[m][np][r] + biasv[np];
        v = v > 0.f ? v : 0.01f*v;
        acc[m][np][r] = v;
        s4[r] += v; q4[r] += v*v;
      }
    #pragma unroll
    for (int off = 1; off < 16; off <<= 1)
      #pragma unroll
      for (int r = 0; r < 4; ++r) {
        s4[r] += __shfl_xor(s4[r], off);
        q4[r] += __shfl_xor(q4[r], off);
      }
    #pragma unroll
    for (int r = 0; r < 4; ++r) {
      float mu = s4[r] * (1.f/128.f);
      float var = q4[r] * (1.f/128.f) - mu*mu;
      float rs = rsqrtf(var + 1e-5f);
      long row = row0 + m*16 + lg*4 + r;
      #pragma unroll
      for (int np = 0; np < 8; ++np)
        hout[row*HH + np*16 + lr] = f2bf((acc[m][np][r]-mu)*rs*gamv[np] + betv[np]);
    }
  }
}

// K2: MFMA minGRU matmul [round-11 green text] — layer 1 only (reads h from HBM).
__global__ __launch_bounds__(256) void gru_mm_kernel(
    const unsigned short* __restrict__ h, const unsigned short* __restrict__ wt,
    const float* __restrict__ bias,
    unsigned* __restrict__ ab, float* __restrict__ AsT, float* __restrict__ BsT)
{
  __shared__ short8 wlds[4096];   // 64 KB
  int tid = threadIdx.x;
  int wid = tid >> 6, lane = tid & 63;
  int chunk = blockIdx.x*4 + wid;
  int b = chunk >> 8, c = chunk & 255;
  long row0 = (long)b*TT + (long)c*CHUNK;
  int lr = lane & 15, lg = lane >> 4;
  int sx = (lane & 7) << 4;

  short8 af[2][4];
  #pragma unroll
  for (int m = 0; m < 2; ++m)
    #pragma unroll
    for (int s = 0; s < 4; ++s)
      af[m][s] = *(const short8*)(h + (row0 + m*16 + lr)*HH + s*32 + lg*8);

  const short8* wsrc = (const short8*)wt;
  #pragma unroll
  for (int i = 0; i < 16; ++i) wlds[i*256 + tid] = wsrc[i*256 + tid];
  __syncthreads();

  const char* wbase = (const char*)wlds;
  #pragma unroll 2
  for (int np = 0; np < 8; ++np) {
    f32x4 acch[2], accg[2];
    #pragma unroll
    for (int m = 0; m < 2; ++m) { acch[m] = (f32x4){0.f,0.f,0.f,0.f}; accg[m] = (f32x4){0.f,0.f,0.f,0.f}; }
    int rh = np*16 + lr;
    int rg = rh + 128;
    #pragma unroll
    for (int s = 0; s < 4; ++s) {
      short8 bh = *(const short8*)(wbase + ((rh*256 + s*64 + lg*16) ^ sx));
      short8 bg = *(const short8*)(wbase + ((rg*256 + s*64 + lg*16) ^ sx));
      #pragma unroll
      for (int m = 0; m < 2; ++m) {
        acch[m] = __builtin_amdgcn_mfma_f32_16x16x32_bf16(af[m][s], bh, acch[m], 0, 0, 0);
        accg[m] = __builtin_amdgcn_mfma_f32_16x16x32_bf16(af[m][s], bg, accg[m], 0, 0, 0);
      }
    }
    int col = np*16 + lr;
    float bh0 = bias[col], bg0 = bias[HH + col];
    float At[2], Bt[2];
    #pragma unroll
    for (int m = 0; m < 2; ++m) {
      float A4 = 1.f, B4 = 0.f;
      #pragma unroll
      for (int r = 0; r < 4; ++r) {
        float hid = acch[m][r] + bh0;
        float z = sigm(accg[m][r] + bg0);
        float gv = hid >= 0.f ? hid + 0.5f : sigm(hid);
        float av = 1.f - z, bv = z*gv;
        size_t grow = (size_t)(row0 + m*16 + lg*4 + r);
        ab[grow*HH + col] = (unsigned)f2bf(av) | ((unsigned)f2bf(bv) << 16);
        A4 *= av; B4 = av*B4 + bv;
      }
      #pragma unroll
      for (int off = 1; off < 4; off <<= 1) {
        float pa = __shfl_up(A4, off*16);
        float pb = __shfl_up(B4, off*16);
        float na = pa*A4, nb = A4*pb + B4;
        if (lg >= off) { A4 = na; B4 = nb; }
      }
      At[m] = __shfl(A4, 48 + lr);
      Bt[m] = __shfl(B4, 48 + lr);
    }
    if (lane < 16) {
      float Ac = At[0]*At[1];
      float Bc = At[1]*Bt[0] + Bt[1];
      size_t sidx = ((size_t)b*128 + col)*256 + c;   // transposed
      AsT[sidx] = Ac;
      BsT[sidx] = Bc;
    }
  }
}

// K3: wave-parallel scan [green text]
__global__ __launch_bounds__(256) void scan2_kernel(
    const float* __restrict__ AsT, const float* __restrict__ BsT, float* __restrict__ carT)
{
  int wid = threadIdx.x >> 6, lane = threadIdx.x & 63;
  int s = blockIdx.x*4 + wid;     // 0..1023 = b*128+d
  float4 Av = ((const float4*)(AsT + (size_t)s*256))[lane];
  float4 Bv = ((const float4*)(BsT + (size_t)s*256))[lane];
  float Ai = Av.x, Bi = Bv.x;
  Bi = Av.y*Bi + Bv.y; Ai = Av.y*Ai;
  Bi = Av.z*Bi + Bv.z; Ai = Av.z*Ai;
  Bi = Av.w*Bi + Bv.w; Ai = Av.w*Ai;
  #pragma unroll
  for (int off = 1; off < 64; off <<= 1) {
    float pA = __shfl_up(Ai, off);
    float pB = __shfl_up(Bi, off);
    if (lane >= off) { Bi = Ai*pB + Bi; Ai = Ai*pA; }
  }
  float exB = __shfl_up(Bi, 1);
  if (lane == 0) exB = 0.f;
  float run = exB;
  float4 cv;
  cv.x = run; run = Av.x*run + Bv.x;
  cv.y = run; run = Av.y*run + Bv.y;
  cv.z = run; run = Av.z*run + Bv.z;
  cv.w = run;
  ((float4*)(carT + (size_t)s*256))[lane] = cv;
}

// K4: FUSED apply(l) + mm(l+1). apply = round-5 green text with destination =
// per-wave LDS h tile (R13-validated swizzle); mm = round-11 green text with af
// read from the tile (R13-validated read pattern). Same bf16 bits as the
// unfused path => bit-identical ab/summaries. h never touches HBM.
// ab reused in place: reads (layer l rows) complete before the barrier; writes
// (layer l+1, same chunk-private rows) after it.
__global__ __launch_bounds__(256) void apply_mm_kernel(
    unsigned* __restrict__ ab, const float* __restrict__ carT,
    const float* __restrict__ g, const float* __restrict__ be,
    const unsigned short* __restrict__ wt, const float* __restrict__ bias,
    float* __restrict__ AsT, float* __restrict__ BsT)
{
  __shared__ short8 wlds[4096];      // 64 KB next-layer weights
  __shared__ unsigned hlds[4*2048];  // 32 KB per-wave h tiles
  int tid = threadIdx.x, wid = tid >> 6, lane = tid & 63;

  // issue weight staging early; the apply phase overlaps its latency
  const short8* wsrc = (const short8*)wt;
  #pragma unroll
  for (int i = 0; i < 16; ++i) wlds[i*256 + tid] = wsrc[i*256 + tid];

  int chunk = blockIdx.x*4 + wid;
  int b = chunk >> 8, c = chunk & 255;
  float2 hc;
  hc.x = carT[((size_t)b*128 + 2*lane    )*256 + c];
  hc.y = carT[((size_t)b*128 + 2*lane + 1)*256 + c];
  float2 gam = ((const float2*)g)[lane];
  float2 bet = ((const float2*)be)[lane];
  size_t rowbase = (size_t)chunk*CHUNK;
  unsigned* myh = hlds + wid*2048;

  // ---- apply phase (round-5 text; destination = swizzled LDS tile) ----
  for (int gq = 0; gq < 4; ++gq) {
    uint2 v[8];
    #pragma unroll
    for (int j = 0; j < 8; ++j)
      v[j] = ((const uint2*)(ab + (rowbase + gq*8 + j)*HH))[lane];
    #pragma unroll
    for (int j = 0; j < 8; ++j) {
      float ax = bf2f(v[j].x & 0xffffu), bx = bf2f(v[j].x >> 16);
      float ay = bf2f(v[j].y & 0xffffu), by = bf2f(v[j].y >> 16);
      hc.x = ax*hc.x + bx;
      hc.y = ay*hc.y + by;
      float s = hc.x + hc.y, q = hc.x*hc.x + hc.y*hc.y;
      #pragma unroll
      for (int m2 = 1; m2 < 64; m2 <<= 1) { s += __shfl_xor(s, m2); q += __shfl_xor(q, m2); }
      float mu = s * (1.f/128.f);
      float var = q * (1.f/128.f) - mu*mu;
      float rs = rsqrtf(var + 1e-5f);
      unsigned o = (unsigned)f2bf((hc.x-mu)*rs*gam.x + bet.x)
                 | ((unsigned)f2bf((hc.y-mu)*rs*gam.y + bet.y) << 16);
      int t = gq*8 + j;
      myh[(t*64 + lane) ^ ((t & 7) << 2)] = o;
    }
  }
  __syncthreads();   // wt staged + all ab reads done + tiles written

  // ---- mm phase (round-11 text; af from tile) ----
  long row0 = (long)b*TT + (long)c*CHUNK;
  int lr = lane & 15, lg = lane >> 4;
  int sx = (lane & 7) << 4;
  short8 af[2][4];
  #pragma unroll
  for (int m = 0; m < 2; ++m)
    #pragma unroll
    for (int s = 0; s < 4; ++s) {
      int row = m*16 + lr;
      af[m][s] = *(const short8*)(myh + (((row*64) + s*16 + lg*4) ^ ((row & 7) << 2)));
    }

  const char* wbase = (const char*)wlds;
  #pragma unroll 2
  for (int np = 0; np < 8; ++np) {
    f32x4 acch[2], accg[2];
    #pragma unroll
    for (int m = 0; m < 2; ++m) { acch[m] = (f32x4){0.f,0.f,0.f,0.f}; accg[m] = (f32x4){0.f,0.f,0.f,0.f}; }
    int rh = np*16 + lr;
    int rg = rh + 128;
    #pragma unroll
    for (int s = 0; s < 4; ++s) {
      short8 bh = *(const short8*)(wbase + ((rh*256 + s*64 + lg*16) ^ sx));
      short8 bg = *(const short8*)(wbase + ((rg*256 + s*64 + lg*16) ^ sx));
      #pragma unroll
      for (int m = 0; m < 2; ++m) {
        acch[m] = __builtin_amdgcn_mfma_f32_16x16x32_bf16(af[m][s], bh, acch[m], 0, 0, 0);
        accg[m] = __builtin_amdgcn_mfma_f32_16x16x32_bf16(af[m][s], bg, accg[m], 0, 0, 0);
      }
    }
    int col = np*16 + lr;
    float bh0 = bias[col], bg0 = bias[HH + col];
    float At[2], Bt[2];
    #pragma unroll
    for (int m = 0; m < 2; ++m) {
      float A4 = 1.f, B4 = 0.f;
      #pragma unroll
      for (int r = 0; r < 4; ++r) {
        float hid = acch[m][r] + bh0;
        float z = sigm(accg[m][r] + bg0);
        float gv = hid >= 0.f ? hid + 0.5f : sigm(hid);
        float av = 1.f - z, bv = z*gv;
        size_t grow = (size_t)(row0 + m*16 + lg*4 + r);
        ab[grow*HH + col] = (unsigned)f2bf(av) | ((unsigned)f2bf(bv) << 16);
        A4 *= av; B4 = av*B4 + bv;
      }
      #pragma unroll
      for (int off = 1; off < 4; off <<= 1) {
        float pa = __shfl_up(A4, off*16);
        float pb = __shfl_up(B4, off*16);
        float na = pa*A4, nb = A4*pb + B4;
        if (lg >= off) { A4 = na; B4 = nb; }
      }
      At[m] = __shfl(A4, 48 + lr);
      Bt[m] = __shfl(B4, 48 + lr);
    }
    if (lane < 16) {
      float Ac = At[0]*At[1];
      float Bc = At[1]*Bt[0] + Bt[1];
      size_t sidx = ((size_t)b*128 + col)*256 + c;
      AsT[sidx] = Ac;
      BsT[sidx] = Bc;
    }
  }
}

// K5 (layer 3): apply + LN -> LDS tile -> proj MFMA + softplus -> out [R13 green text]
__global__ __launch_bounds__(256) void apply_proj_kernel(
    const unsigned* __restrict__ ab, const float* __restrict__ carT,
    const float* __restrict__ g, const float* __restrict__ be,
    const unsigned short* __restrict__ wt_p, const float* __restrict__ pb,
    float* __restrict__ out)
{
  __shared__ short8 wlds[1024];        // 16 KB proj weights
  __shared__ unsigned hlds[4*2048];    // 32 KB per-wave h tiles
  int tid = threadIdx.x, wid = tid >> 6, lane = tid & 63;
  const short8* wsrc = (const short8*)wt_p;
  #pragma unroll
  for (int i = 0; i < 4; ++i) wlds[i*256 + tid] = wsrc[i*256 + tid];

  int chunk = blockIdx.x*4 + wid;
  int b = chunk >> 8, c = chunk & 255;
  float2 hc;
  hc.x = carT[((size_t)b*128 + 2*lane    )*256 + c];
  hc.y = carT[((size_t)b*128 + 2*lane + 1)*256 + c];
  float2 gam = ((const float2*)g)[lane];
  float2 bet = ((const float2*)be)[lane];
  size_t rowbase = (size_t)chunk*CHUNK;
  unsigned* myh = hlds + wid*2048;

  for (int gq = 0; gq < 4; ++gq) {
    uint2 v[8];
    #pragma unroll
    for (int j = 0; j < 8; ++j)
      v[j] = ((const uint2*)(ab + (rowbase + gq*8 + j)*HH))[lane];
    #pragma unroll
    for (int j = 0; j < 8; ++j) {
      float ax = bf2f(v[j].x & 0xffffu), bx = bf2f(v[j].x >> 16);
      float ay = bf2f(v[j].y & 0xffffu), by = bf2f(v[j].y >> 16);
      hc.x = ax*hc.x + bx;
      hc.y = ay*hc.y + by;
      float s = hc.x + hc.y, q = hc.x*hc.x + hc.y*hc.y;
      #pragma unroll
      for (int m2 = 1; m2 < 64; m2 <<= 1) { s += __shfl_xor(s, m2); q += __shfl_xor(q, m2); }
      float mu = s * (1.f/128.f);
      float var = q * (1.f/128.f) - mu*mu;
      float rs = rsqrtf(var + 1e-5f);
      unsigned o = (unsigned)f2bf((hc.x-mu)*rs*gam.x + bet.x)
                 | ((unsigned)f2bf((hc.y-mu)*rs*gam.y + bet.y) << 16);
      int t = gq*8 + j;
      myh[(t*64 + lane) ^ ((t & 7) << 2)] = o;
    }
  }
  __syncthreads();

  int lr = lane & 15, lg = lane >> 4;
  int sx = (lane & 7) << 4;
  short8 af[2][4];
  #pragma unroll
  for (int m = 0; m < 2; ++m)
    #pragma unroll
    for (int s = 0; s < 4; ++s) {
      int row = m*16 + lr;
      af[m][s] = *(const short8*)(myh + (((row*64) + s*16 + lg*4) ^ ((row & 7) << 2)));
    }

  const char* wbase = (const char*)wlds;
  f32x4 acc[2][4];
  #pragma unroll
  for (int m = 0; m < 2; ++m)
    #pragma unroll
    for (int np = 0; np < 4; ++np) acc[m][np] = (f32x4){0.f,0.f,0.f,0.f};

  #pragma unroll
  for (int np = 0; np < 4; ++np) {
    int col = np*16 + lr;
    #pragma unroll
    for (int s = 0; s < 4; ++s) {
      short8 bh = *(const short8*)(wbase + ((col*256 + s*64 + lg*16) ^ sx));
      #pragma unroll
      for (int m = 0; m < 2; ++m)
        acc[m][np] = __builtin_amdgcn_mfma_f32_16x16x32_bf16(af[m][s], bh, acc[m][np], 0, 0, 0);
    }
  }

  #pragma unroll
  for (int np = 0; np < 4; ++np) {
    int col = np*16 + lr;
    bool act = col < 50;
    float bias = act ? pb[col] : 0.f;
    #pragma unroll
    for (int m = 0; m < 2; ++m)
      #pragma unroll
      for (int r = 0; r < 4; ++r) {
        float v = acc[m][np][r] + bias;
        float sp = fmaxf(v, 0.f) + log1pf(__expf(-fabsf(v)));
        if (act) out[(rowbase + m*16 + lg*4 + r)*50 + col] = sp;
      }
  }
}

extern "C" void kernel_launch(void* const* d_in, const int* in_sizes, int n_in,
                              void* d_out, int out_size, void* d_ws, size_t ws_size,
                              hipStream_t stream) {
  const float* x    = (const float*)d_in[0];
  const float* ew   = (const float*)d_in[1];
  const float* eb   = (const float*)d_in[2];
  const float* ln0g = (const float*)d_in[3];
  const float* ln0b = (const float*)d_in[4];
  const float* pw   = (const float*)d_in[5];
  const float* pb   = (const float*)d_in[6];
  float* out = (float*)d_out;

  size_t nBT  = (size_t)BB*TT*HH;
  size_t nSum = (size_t)BB*NC*HH;
  unsigned short* h  = (unsigned short*)d_ws;
  unsigned*       ab = (unsigned*)(h + nBT);
  float* AsT  = (float*)(ab + nBT);
  float* BsT  = AsT + nSum;
  float* carT = BsT + nSum;
  unsigned short* wt   = (unsigned short*)(carT + nSum);
  unsigned short* wt_e = wt + 3*32768;
  unsigned short* wt_p = wt_e + 8192;

  prep_kernel<<<448, 256, 0, stream>>>((const float*)d_in[7], (const float*)d_in[11],
                                       (const float*)d_in[15], ew, pw, wt, wt_e, wt_p);
  embed_mfma_kernel<<<(BB*TT)/128, 256, 0, stream>>>(x, wt_e, eb, ln0g, ln0b, h);

  // layer 1 matmul
  gru_mm_kernel<<<(BB*NC)/4, 256, 0, stream>>>(h, wt, (const float*)d_in[8], ab, AsT, BsT);
  scan2_kernel<<<256, 256, 0, stream>>>(AsT, BsT, carT);

  // apply(1) + mm(2)
  apply_mm_kernel<<<(BB*NC)/4, 256, 0, stream>>>(ab, carT,
      (const float*)d_in[9], (const float*)d_in[10],
      wt + 32768, (const float*)d_in[12], AsT, BsT);
  scan2_kernel<<<256, 256, 0, stream>>>(AsT, BsT, carT);

  // apply(2) + mm(3)
  apply_mm_kernel<<<(BB*NC)/4, 256, 0, stream>>>(ab, carT,
      (const float*)d_in[13], (const float*)d_in[14],
      wt + 65536, (const float*)d_in[16], AsT, BsT);
  scan2_kernel<<<256, 256, 0, stream>>>(AsT, BsT, carT);

  // apply(3) + proj
  apply_proj_kernel<<<(BB*NC)/4, 256, 0, stream>>>(ab, carT,
      (const float*)d_in[17], (const float*)d_in[18], wt_p, pb, out);
}

// Round 15
// 139.047 us; speedup vs baseline: 1.0983x; 1.0983x over previous
//
#include <hip/hip_runtime.h>
#include <math.h>

#define BB 8
#define TT 8192
#define XX 64
#define HH 128
#define CHUNK 32
#define NC (TT/CHUNK)

typedef __attribute__((ext_vector_type(8))) short short8;
typedef __attribute__((ext_vector_type(4))) float f32x4;

// fast sigmoid: v_rcp_f32 (~1 ulp) instead of IEEE div sequence.
__device__ __forceinline__ float sigm(float x){
  return __builtin_amdgcn_rcpf(1.0f + __expf(-x));
}
__device__ __forceinline__ unsigned short f2bf(float f){
  unsigned u = __float_as_uint(f);
  return (unsigned short)((u + 0x7fffu + ((u>>16)&1u)) >> 16);
}
__device__ __forceinline__ float bf2f(unsigned b){ return __uint_as_float(b << 16); }
// single-instruction pack: lo -> bits[15:0], hi -> bits[31:16] (RNE), replaces
// two f2bf bit-twiddles + shift/or (~9 VALU ops -> 1).
__device__ __forceinline__ unsigned pk_bf16(float lo, float hi){
  unsigned r;
  asm("v_cvt_pk_bf16_f32 %0, %1, %2" : "=v"(r) : "v"(lo), "v"(hi));
  return r;
}

// P0: build bf16 weight tables, pre-swizzled (byte ^= (col&7)<<4).
__global__ __launch_bounds__(256) void prep_kernel(
    const float* __restrict__ w1, const float* __restrict__ w2, const float* __restrict__ w3,
    const float* __restrict__ ew, const float* __restrict__ pw,
    unsigned short* __restrict__ wt, unsigned short* __restrict__ wt_e, unsigned short* __restrict__ wt_p)
{
  int idx = blockIdx.x*256 + threadIdx.x;
  if (idx < 98304) {
    int l = idx >> 15;
    int e = idx & 32767;
    int k = e >> 8;
    int col = e & 255;
    const float* w = (l==0) ? w1 : ((l==1) ? w2 : w3);
    float v = w[e];
    unsigned byte = ((unsigned)col*128u + (unsigned)k)*2u;
    byte ^= (unsigned)((col & 7) << 4);
    wt[(size_t)l*32768 + (byte >> 1)] = f2bf(v);
  } else if (idx < 106496) {
    int e = idx - 98304;
    int col = e >> 6, k = e & 63;
    float v = ew[k*HH + col];
    unsigned byte = ((unsigned)e*2u) ^ (unsigned)((col & 7) << 4);
    wt_e[byte >> 1] = f2bf(v);
  } else if (idx < 114688) {
    int e = idx - 106496;
    int col = e >> 7, k = e & 127;
    float v = (col < 50) ? pw[k*50 + col] : 0.f;
    unsigned byte = ((unsigned)e*2u) ^ (unsigned)((col & 7) << 4);
    wt_p[byte >> 1] = f2bf(v);
  }
}

// K1: embed (64->128) MFMA + leaky_relu + LN0 -> h (bf16)   [green text]
__global__ __launch_bounds__(256) void embed_mfma_kernel(
    const float* __restrict__ x, const unsigned short* __restrict__ wt_e,
    const float* __restrict__ eb, const float* __restrict__ g, const float* __restrict__ be,
    unsigned short* __restrict__ hout)
{
  __shared__ short8 wlds[1024];
  int tid = threadIdx.x;
  const short8* wsrc = (const short8*)wt_e;
  #pragma unroll
  for (int i = 0; i < 4; ++i) wlds[i*256 + tid] = wsrc[i*256 + tid];

  int wid = tid >> 6, lane = tid & 63;
  int lr = lane & 15, lg = lane >> 4;
  int sx = (lane & 7) << 4;
  long row0 = (long)(blockIdx.x*4 + wid)*32;

  short8 af[2][2];
  #pragma unroll
  for (int m = 0; m < 2; ++m)
    #pragma unroll
    for (int s = 0; s < 2; ++s) {
      const float* xp = x + (row0 + m*16 + lr)*XX + s*32 + lg*8;
      float4 u0 = *(const float4*)xp;
      float4 u1 = *(const float4*)(xp + 4);
      short8 t;
      t[0]=f2bf(u0.x); t[1]=f2bf(u0.y); t[2]=f2bf(u0.z); t[3]=f2bf(u0.w);
      t[4]=f2bf(u1.x); t[5]=f2bf(u1.y); t[6]=f2bf(u1.z); t[7]=f2bf(u1.w);
      af[m][s] = t;
    }
  __syncthreads();

  const char* wbase = (const char*)wlds;
  f32x4 acc[2][8];
  #pragma unroll
  for (int m = 0; m < 2; ++m)
    #pragma unroll
    for (int np = 0; np < 8; ++np) acc[m][np] = (f32x4){0.f,0.f,0.f,0.f};

  #pragma unroll
  for (int np = 0; np < 8; ++np) {
    int col = np*16 + lr;
    #pragma unroll
    for (int s = 0; s < 2; ++s) {
      short8 bh = *(const short8*)(wbase + ((col*128 + s*64 + lg*16) ^ sx));
      #pragma unroll
      for (int m = 0; m < 2; ++m)
        acc[m][np] = __builtin_amdgcn_mfma_f32_16x16x32_bf16(af[m][s], bh, acc[m][np], 0, 0, 0);
    }
  }

  float gamv[8], betv[8], biasv[8];
  #pragma unroll
  for (int np = 0; np < 8; ++np) {
    int col = np*16 + lr;
    gamv[np] = g[col]; betv[np] = be[col]; biasv[np] = eb[col];
  }

  #pragma unroll
  for (int m = 0; m < 2; ++m) {
    float s4[4], q4[4];
    #pragma unroll
    for (int r = 0; r < 4; ++r) { s4[r] = 0.f; q4[r] = 0.f; }
    #pragma unroll
    for (int np = 0; np < 8; ++np)
      #pragma unroll
      for (int r = 0; r < 4; ++r) {
        float v = acc[m][np][r] + biasv[np];
        v = v > 0.f ? v : 0.01f*v;
        acc[m][np][r] = v;
        s4[r] += v; q4[r] += v*v;
      }
    #pragma unroll
    for (int off = 1; off < 16; off <<= 1)
      #pragma unroll
      for (int r = 0; r < 4; ++r) {
        s4[r] += __shfl_xor(s4[r], off);
        q4[r] += __shfl_xor(q4[r], off);
      }
    #pragma unroll
    for (int r = 0; r < 4; ++r) {
      float mu = s4[r] * (1.f/128.f);
      float var = q4[r] * (1.f/128.f) - mu*mu;
      float rs = rsqrtf(var + 1e-5f);
      long row = row0 + m*16 + lg*4 + r;
      #pragma unroll
      for (int np = 0; np < 8; ++np)
        hout[row*HH + np*16 + lr] = f2bf((acc[m][np][r]-mu)*rs*gamv[np] + betv[np]);
    }
  }
}

// K2: MFMA minGRU matmul [round-11 green text, + cvt_pk ab pack]
__global__ __launch_bounds__(256) void gru_mm_kernel(
    const unsigned short* __restrict__ h, const unsigned short* __restrict__ wt,
    const float* __restrict__ bias,
    unsigned* __restrict__ ab, float* __restrict__ AsT, float* __restrict__ BsT)
{
  __shared__ short8 wlds[4096];   // 64 KB
  int tid = threadIdx.x;
  int wid = tid >> 6, lane = tid & 63;
  int chunk = blockIdx.x*4 + wid;
  int b = chunk >> 8, c = chunk & 255;
  long row0 = (long)b*TT + (long)c*CHUNK;
  int lr = lane & 15, lg = lane >> 4;
  int sx = (lane & 7) << 4;

  short8 af[2][4];
  #pragma unroll
  for (int m = 0; m < 2; ++m)
    #pragma unroll
    for (int s = 0; s < 4; ++s)
      af[m][s] = *(const short8*)(h + (row0 + m*16 + lr)*HH + s*32 + lg*8);

  const short8* wsrc = (const short8*)wt;
  #pragma unroll
  for (int i = 0; i < 16; ++i) wlds[i*256 + tid] = wsrc[i*256 + tid];
  __syncthreads();

  const char* wbase = (const char*)wlds;
  #pragma unroll 2
  for (int np = 0; np < 8; ++np) {
    f32x4 acch[2], accg[2];
    #pragma unroll
    for (int m = 0; m < 2; ++m) { acch[m] = (f32x4){0.f,0.f,0.f,0.f}; accg[m] = (f32x4){0.f,0.f,0.f,0.f}; }
    int rh = np*16 + lr;
    int rg = rh + 128;
    #pragma unroll
    for (int s = 0; s < 4; ++s) {
      short8 bh = *(const short8*)(wbase + ((rh*256 + s*64 + lg*16) ^ sx));
      short8 bg = *(const short8*)(wbase + ((rg*256 + s*64 + lg*16) ^ sx));
      #pragma unroll
      for (int m = 0; m < 2; ++m) {
        acch[m] = __builtin_amdgcn_mfma_f32_16x16x32_bf16(af[m][s], bh, acch[m], 0, 0, 0);
        accg[m] = __builtin_amdgcn_mfma_f32_16x16x32_bf16(af[m][s], bg, accg[m], 0, 0, 0);
      }
    }
    int col = np*16 + lr;
    float bh0 = bias[col], bg0 = bias[HH + col];
    float At[2], Bt[2];
    #pragma unroll
    for (int m = 0; m < 2; ++m) {
      float A4 = 1.f, B4 = 0.f;
      #pragma unroll
      for (int r = 0; r < 4; ++r) {
        float hid = acch[m][r] + bh0;
        float z = sigm(accg[m][r] + bg0);
        float gv = hid >= 0.f ? hid + 0.5f : sigm(hid);
        float av = 1.f - z, bv = z*gv;
        size_t grow = (size_t)(row0 + m*16 + lg*4 + r);
        ab[grow*HH + col] = pk_bf16(av, bv);
        A4 *= av; B4 = av*B4 + bv;
      }
      #pragma unroll
      for (int off = 1; off < 4; off <<= 1) {
        float pa = __shfl_up(A4, off*16);
        float pb = __shfl_up(B4, off*16);
        float na = pa*A4, nb = A4*pb + B4;
        if (lg >= off) { A4 = na; B4 = nb; }
      }
      At[m] = __shfl(A4, 48 + lr);
      Bt[m] = __shfl(B4, 48 + lr);
    }
    if (lane < 16) {
      float Ac = At[0]*At[1];
      float Bc = At[1]*Bt[0] + Bt[1];
      size_t sidx = ((size_t)b*128 + col)*256 + c;   // transposed
      AsT[sidx] = Ac;
      BsT[sidx] = Bc;
    }
  }
}

// K3: wave-parallel scan [green text]
__global__ __launch_bounds__(256) void scan2_kernel(
    const float* __restrict__ AsT, const float* __restrict__ BsT, float* __restrict__ carT)
{
  int wid = threadIdx.x >> 6, lane = threadIdx.x & 63;
  int s = blockIdx.x*4 + wid;     // 0..1023 = b*128+d
  float4 Av = ((const float4*)(AsT + (size_t)s*256))[lane];
  float4 Bv = ((const float4*)(BsT + (size_t)s*256))[lane];
  float Ai = Av.x, Bi = Bv.x;
  Bi = Av.y*Bi + Bv.y; Ai = Av.y*Ai;
  Bi = Av.z*Bi + Bv.z; Ai = Av.z*Ai;
  Bi = Av.w*Bi + Bv.w; Ai = Av.w*Ai;
  #pragma unroll
  for (int off = 1; off < 64; off <<= 1) {
    float pA = __shfl_up(Ai, off);
    float pB = __shfl_up(Bi, off);
    if (lane >= off) { Bi = Ai*pB + Bi; Ai = Ai*pA; }
  }
  float exB = __shfl_up(Bi, 1);
  if (lane == 0) exB = 0.f;
  float run = exB;
  float4 cv;
  cv.x = run; run = Av.x*run + Bv.x;
  cv.y = run; run = Av.y*run + Bv.y;
  cv.z = run; run = Av.z*run + Bv.z;
  cv.w = run;
  ((float4*)(carT + (size_t)s*256))[lane] = cv;
}

// K4: apply recurrence + fused LN -> h (bf16). [round-5 green text + cvt_pk pack]
__global__ __launch_bounds__(256) void apply_kernel(
    const unsigned* __restrict__ ab, const float* __restrict__ carT,
    const float* __restrict__ g, const float* __restrict__ be,
    unsigned short* __restrict__ hout)
{
  int tid = threadIdx.x, wid = tid >> 6, lane = tid & 63;
  int chunk = blockIdx.x*4 + wid;
  int b = chunk >> 8, c = chunk & 255;
  float2 hc;
  hc.x = carT[((size_t)b*128 + 2*lane    )*256 + c];
  hc.y = carT[((size_t)b*128 + 2*lane + 1)*256 + c];
  float2 gam = ((const float2*)g)[lane];
  float2 bet = ((const float2*)be)[lane];
  size_t rowbase = (size_t)chunk*CHUNK;
  for (int gq = 0; gq < 4; ++gq) {
    uint2 v[8];
    #pragma unroll
    for (int j = 0; j < 8; ++j)
      v[j] = ((const uint2*)(ab + (rowbase + gq*8 + j)*HH))[lane];
    #pragma unroll
    for (int j = 0; j < 8; ++j) {
      float ax = bf2f(v[j].x & 0xffffu), bx = bf2f(v[j].x >> 16);
      float ay = bf2f(v[j].y & 0xffffu), by = bf2f(v[j].y >> 16);
      hc.x = ax*hc.x + bx;
      hc.y = ay*hc.y + by;
      float s = hc.x + hc.y, q = hc.x*hc.x + hc.y*hc.y;
      #pragma unroll
      for (int m = 1; m < 64; m <<= 1) { s += __shfl_xor(s, m); q += __shfl_xor(q, m); }
      float mu = s * (1.f/128.f);
      float var = q * (1.f/128.f) - mu*mu;
      float rs = rsqrtf(var + 1e-5f);
      unsigned o = pk_bf16((hc.x-mu)*rs*gam.x + bet.x, (hc.y-mu)*rs*gam.y + bet.y);
      ((unsigned*)hout)[(rowbase + gq*8 + j)*64 + lane] = o;
    }
  }
}

// K5 (layer 3): apply + LN -> LDS tile -> proj MFMA + softplus -> out
// [R13 green text + cvt_pk pack]
__global__ __launch_bounds__(256) void apply_proj_kernel(
    const unsigned* __restrict__ ab, const float* __restrict__ carT,
    const float* __restrict__ g, const float* __restrict__ be,
    const unsigned short* __restrict__ wt_p, const float* __restrict__ pb,
    float* __restrict__ out)
{
  __shared__ short8 wlds[1024];        // 16 KB proj weights
  __shared__ unsigned hlds[4*2048];    // 32 KB per-wave h tiles
  int tid = threadIdx.x, wid = tid >> 6, lane = tid & 63;
  const short8* wsrc = (const short8*)wt_p;
  #pragma unroll
  for (int i = 0; i < 4; ++i) wlds[i*256 + tid] = wsrc[i*256 + tid];

  int chunk = blockIdx.x*4 + wid;
  int b = chunk >> 8, c = chunk & 255;
  float2 hc;
  hc.x = carT[((size_t)b*128 + 2*lane    )*256 + c];
  hc.y = carT[((size_t)b*128 + 2*lane + 1)*256 + c];
  float2 gam = ((const float2*)g)[lane];
  float2 bet = ((const float2*)be)[lane];
  size_t rowbase = (size_t)chunk*CHUNK;
  unsigned* myh = hlds + wid*2048;

  for (int gq = 0; gq < 4; ++gq) {
    uint2 v[8];
    #pragma unroll
    for (int j = 0; j < 8; ++j)
      v[j] = ((const uint2*)(ab + (rowbase + gq*8 + j)*HH))[lane];
    #pragma unroll
    for (int j = 0; j < 8; ++j) {
      float ax = bf2f(v[j].x & 0xffffu), bx = bf2f(v[j].x >> 16);
      float ay = bf2f(v[j].y & 0xffffu), by = bf2f(v[j].y >> 16);
      hc.x = ax*hc.x + bx;
      hc.y = ay*hc.y + by;
      float s = hc.x + hc.y, q = hc.x*hc.x + hc.y*hc.y;
      #pragma unroll
      for (int m2 = 1; m2 < 64; m2 <<= 1) { s += __shfl_xor(s, m2); q += __shfl_xor(q, m2); }
      float mu = s * (1.f/128.f);
      float var = q * (1.f/128.f) - mu*mu;
      float rs = rsqrtf(var + 1e-5f);
      unsigned o = pk_bf16((hc.x-mu)*rs*gam.x + bet.x, (hc.y-mu)*rs*gam.y + bet.y);
      int t = gq*8 + j;
      myh[(t*64 + lane) ^ ((t & 7) << 2)] = o;
    }
  }
  __syncthreads();

  int lr = lane & 15, lg = lane >> 4;
  int sx = (lane & 7) << 4;
  short8 af[2][4];
  #pragma unroll
  for (int m = 0; m < 2; ++m)
    #pragma unroll
    for (int s = 0; s < 4; ++s) {
      int row = m*16 + lr;
      af[m][s] = *(const short8*)(myh + (((row*64) + s*16 + lg*4) ^ ((row & 7) << 2)));
    }

  const char* wbase = (const char*)wlds;
  f32x4 acc[2][4];
  #pragma unroll
  for (int m = 0; m < 2; ++m)
    #pragma unroll
    for (int np = 0; np < 4; ++np) acc[m][np] = (f32x4){0.f,0.f,0.f,0.f};

  #pragma unroll
  for (int np = 0; np < 4; ++np) {
    int col = np*16 + lr;
    #pragma unroll
    for (int s = 0; s < 4; ++s) {
      short8 bh = *(const short8*)(wbase + ((col*256 + s*64 + lg*16) ^ sx));
      #pragma unroll
      for (int m = 0; m < 2; ++m)
        acc[m][np] = __builtin_amdgcn_mfma_f32_16x16x32_bf16(af[m][s], bh, acc[m][np], 0, 0, 0);
    }
  }

  #pragma unroll
  for (int np = 0; np < 4; ++np) {
    int col = np*16 + lr;
    bool act = col < 50;
    float bias = act ? pb[col] : 0.f;
    #pragma unroll
    for (int m = 0; m < 2; ++m)
      #pragma unroll
      for (int r = 0; r < 4; ++r) {
        float v = acc[m][np][r] + bias;
        float sp = fmaxf(v, 0.f) + log1pf(__expf(-fabsf(v)));
        if (act) out[(rowbase + m*16 + lg*4 + r)*50 + col] = sp;
      }
  }
}

extern "C" void kernel_launch(void* const* d_in, const int* in_sizes, int n_in,
                              void* d_out, int out_size, void* d_ws, size_t ws_size,
                              hipStream_t stream) {
  const float* x    = (const float*)d_in[0];
  const float* ew   = (const float*)d_in[1];
  const float* eb   = (const float*)d_in[2];
  const float* ln0g = (const float*)d_in[3];
  const float* ln0b = (const float*)d_in[4];
  const float* pw   = (const float*)d_in[5];
  const float* pb   = (const float*)d_in[6];
  float* out = (float*)d_out;

  size_t nBT  = (size_t)BB*TT*HH;
  size_t nSum = (size_t)BB*NC*HH;
  unsigned short* h  = (unsigned short*)d_ws;
  unsigned*       ab = (unsigned*)(h + nBT);
  float* AsT  = (float*)(ab + nBT);
  float* BsT  = AsT + nSum;
  float* carT = BsT + nSum;
  unsigned short* wt   = (unsigned short*)(carT + nSum);
  unsigned short* wt_e = wt + 3*32768;
  unsigned short* wt_p = wt_e + 8192;

  prep_kernel<<<448, 256, 0, stream>>>((const float*)d_in[7], (const float*)d_in[11],
                                       (const float*)d_in[15], ew, pw, wt, wt_e, wt_p);
  embed_mfma_kernel<<<(BB*TT)/128, 256, 0, stream>>>(x, wt_e, eb, ln0g, ln0b, h);

  for (int l = 0; l < 3; ++l) {
    const float* gb = (const float*)d_in[8 + 4*l];
    const float* lg = (const float*)d_in[9 + 4*l];
    const float* lb = (const float*)d_in[10 + 4*l];
    gru_mm_kernel<<<(BB*NC)/4, 256, 0, stream>>>(h, wt + (size_t)l*32768, gb, ab, AsT, BsT);
    scan2_kernel<<<256, 256, 0, stream>>>(AsT, BsT, carT);
    if (l < 2) {
      apply_kernel<<<(BB*NC)/4, 256, 0, stream>>>(ab, carT, lg, lb, h);
    } else {
      apply_proj_kernel<<<(BB*NC)/4, 256, 0, stream>>>(ab, carT, lg, lb, wt_p, pb, out);
    }
  }
}

// Round 16
// 138.928 us; speedup vs baseline: 1.0992x; 1.0009x over previous
//
#include <hip/hip_runtime.h>
#include <math.h>

#define BB 8
#define TT 8192
#define XX 64
#define HH 128
#define CHUNK 32
#define NC (TT/CHUNK)

typedef __attribute__((ext_vector_type(8))) short short8;
typedef __attribute__((ext_vector_type(4))) float f32x4;

// fast sigmoid: v_rcp_f32 (~1 ulp) instead of IEEE div sequence.
__device__ __forceinline__ float sigm(float x){
  return __builtin_amdgcn_rcpf(1.0f + __expf(-x));
}
__device__ __forceinline__ unsigned short f2bf(float f){
  unsigned u = __float_as_uint(f);
  return (unsigned short)((u + 0x7fffu + ((u>>16)&1u)) >> 16);
}
__device__ __forceinline__ float bf2f(unsigned b){ return __uint_as_float(b << 16); }
// single-instruction pack: lo -> bits[15:0], hi -> bits[31:16] (RNE).
__device__ __forceinline__ unsigned pk_bf16(float lo, float hi){
  unsigned r;
  asm("v_cvt_pk_bf16_f32 %0, %1, %2" : "=v"(r) : "v"(lo), "v"(hi));
  return r;
}

// P0: build bf16 weight tables, pre-swizzled (byte ^= (col&7)<<4).
__global__ __launch_bounds__(256) void prep_kernel(
    const float* __restrict__ w1, const float* __restrict__ w2, const float* __restrict__ w3,
    const float* __restrict__ ew, const float* __restrict__ pw,
    unsigned short* __restrict__ wt, unsigned short* __restrict__ wt_e, unsigned short* __restrict__ wt_p)
{
  int idx = blockIdx.x*256 + threadIdx.x;
  if (idx < 98304) {
    int l = idx >> 15;
    int e = idx & 32767;
    int k = e >> 8;
    int col = e & 255;
    const float* w = (l==0) ? w1 : ((l==1) ? w2 : w3);
    float v = w[e];
    unsigned byte = ((unsigned)col*128u + (unsigned)k)*2u;
    byte ^= (unsigned)((col & 7) << 4);
    wt[(size_t)l*32768 + (byte >> 1)] = f2bf(v);
  } else if (idx < 106496) {
    int e = idx - 98304;
    int col = e >> 6, k = e & 63;
    float v = ew[k*HH + col];
    unsigned byte = ((unsigned)e*2u) ^ (unsigned)((col & 7) << 4);
    wt_e[byte >> 1] = f2bf(v);
  } else if (idx < 114688) {
    int e = idx - 106496;
    int col = e >> 7, k = e & 127;
    float v = (col < 50) ? pw[k*50 + col] : 0.f;
    unsigned byte = ((unsigned)e*2u) ^ (unsigned)((col & 7) << 4);
    wt_p[byte >> 1] = f2bf(v);
  }
}

// K1: embed (64->128) MFMA + leaky_relu + LN0 -> h (bf16)  [green text + pk conversions]
__global__ __launch_bounds__(256) void embed_mfma_kernel(
    const float* __restrict__ x, const unsigned short* __restrict__ wt_e,
    const float* __restrict__ eb, const float* __restrict__ g, const float* __restrict__ be,
    unsigned short* __restrict__ hout)
{
  __shared__ short8 wlds[1024];
  int tid = threadIdx.x;
  const short8* wsrc = (const short8*)wt_e;
  #pragma unroll
  for (int i = 0; i < 4; ++i) wlds[i*256 + tid] = wsrc[i*256 + tid];

  int wid = tid >> 6, lane = tid & 63;
  int lr = lane & 15, lg = lane >> 4;
  int sx = (lane & 7) << 4;
  long row0 = (long)(blockIdx.x*4 + wid)*32;

  short8 af[2][2];
  #pragma unroll
  for (int m = 0; m < 2; ++m)
    #pragma unroll
    for (int s = 0; s < 2; ++s) {
      const float* xp = x + (row0 + m*16 + lr)*XX + s*32 + lg*8;
      float4 u0 = *(const float4*)xp;
      float4 u1 = *(const float4*)(xp + 4);
      uint4 t;
      t.x = pk_bf16(u0.x, u0.y); t.y = pk_bf16(u0.z, u0.w);
      t.z = pk_bf16(u1.x, u1.y); t.w = pk_bf16(u1.z, u1.w);
      af[m][s] = *reinterpret_cast<short8*>(&t);
    }
  __syncthreads();

  const char* wbase = (const char*)wlds;
  f32x4 acc[2][8];
  #pragma unroll
  for (int m = 0; m < 2; ++m)
    #pragma unroll
    for (int np = 0; np < 8; ++np) acc[m][np] = (f32x4){0.f,0.f,0.f,0.f};

  #pragma unroll
  for (int np = 0; np < 8; ++np) {
    int col = np*16 + lr;
    #pragma unroll
    for (int s = 0; s < 2; ++s) {
      short8 bh = *(const short8*)(wbase + ((col*128 + s*64 + lg*16) ^ sx));
      #pragma unroll
      for (int m = 0; m < 2; ++m)
        acc[m][np] = __builtin_amdgcn_mfma_f32_16x16x32_bf16(af[m][s], bh, acc[m][np], 0, 0, 0);
    }
  }

  float gamv[8], betv[8], biasv[8];
  #pragma unroll
  for (int np = 0; np < 8; ++np) {
    int col = np*16 + lr;
    gamv[np] = g[col]; betv[np] = be[col]; biasv[np] = eb[col];
  }

  #pragma unroll
  for (int m = 0; m < 2; ++m) {
    float s4[4], q4[4];
    #pragma unroll
    for (int r = 0; r < 4; ++r) { s4[r] = 0.f; q4[r] = 0.f; }
    #pragma unroll
    for (int np = 0; np < 8; ++np)
      #pragma unroll
      for (int r = 0; r < 4; ++r) {
        float v = acc[m][np][r] + biasv[np];
        v = v > 0.f ? v : 0.01f*v;
        acc[m][np][r] = v;
        s4[r] += v; q4[r] += v*v;
      }
    #pragma unroll
    for (int off = 1; off < 16; off <<= 1)
      #pragma unroll
      for (int r = 0; r < 4; ++r) {
        s4[r] += __shfl_xor(s4[r], off);
        q4[r] += __shfl_xor(q4[r], off);
      }
    #pragma unroll
    for (int r = 0; r < 4; ++r) {
      float mu = s4[r] * (1.f/128.f);
      float var = q4[r] * (1.f/128.f) - mu*mu;
      float rs = rsqrtf(var + 1e-5f);
      long row = row0 + m*16 + lg*4 + r;
      #pragma unroll
      for (int np = 0; np < 8; ++np)
        hout[row*HH + np*16 + lr] = f2bf((acc[m][np][r]-mu)*rs*gamv[np] + betv[np]);
    }
  }
}

// K2: MFMA minGRU matmul [round-15 green text]
__global__ __launch_bounds__(256) void gru_mm_kernel(
    const unsigned short* __restrict__ h, const unsigned short* __restrict__ wt,
    const float* __restrict__ bias,
    unsigned* __restrict__ ab, float* __restrict__ AsT, float* __restrict__ BsT)
{
  __shared__ short8 wlds[4096];   // 64 KB
  int tid = threadIdx.x;
  int wid = tid >> 6, lane = tid & 63;
  int chunk = blockIdx.x*4 + wid;
  int b = chunk >> 8, c = chunk & 255;
  long row0 = (long)b*TT + (long)c*CHUNK;
  int lr = lane & 15, lg = lane >> 4;
  int sx = (lane & 7) << 4;

  short8 af[2][4];
  #pragma unroll
  for (int m = 0; m < 2; ++m)
    #pragma unroll
    for (int s = 0; s < 4; ++s)
      af[m][s] = *(const short8*)(h + (row0 + m*16 + lr)*HH + s*32 + lg*8);

  const short8* wsrc = (const short8*)wt;
  #pragma unroll
  for (int i = 0; i < 16; ++i) wlds[i*256 + tid] = wsrc[i*256 + tid];
  __syncthreads();

  const char* wbase = (const char*)wlds;
  #pragma unroll 2
  for (int np = 0; np < 8; ++np) {
    f32x4 acch[2], accg[2];
    #pragma unroll
    for (int m = 0; m < 2; ++m) { acch[m] = (f32x4){0.f,0.f,0.f,0.f}; accg[m] = (f32x4){0.f,0.f,0.f,0.f}; }
    int rh = np*16 + lr;
    int rg = rh + 128;
    #pragma unroll
    for (int s = 0; s < 4; ++s) {
      short8 bh = *(const short8*)(wbase + ((rh*256 + s*64 + lg*16) ^ sx));
      short8 bg = *(const short8*)(wbase + ((rg*256 + s*64 + lg*16) ^ sx));
      #pragma unroll
      for (int m = 0; m < 2; ++m) {
        acch[m] = __builtin_amdgcn_mfma_f32_16x16x32_bf16(af[m][s], bh, acch[m], 0, 0, 0);
        accg[m] = __builtin_amdgcn_mfma_f32_16x16x32_bf16(af[m][s], bg, accg[m], 0, 0, 0);
      }
    }
    int col = np*16 + lr;
    float bh0 = bias[col], bg0 = bias[HH + col];
    float At[2], Bt[2];
    #pragma unroll
    for (int m = 0; m < 2; ++m) {
      float A4 = 1.f, B4 = 0.f;
      #pragma unroll
      for (int r = 0; r < 4; ++r) {
        float hid = acch[m][r] + bh0;
        float z = sigm(accg[m][r] + bg0);
        float gv = hid >= 0.f ? hid + 0.5f : sigm(hid);
        float av = 1.f - z, bv = z*gv;
        size_t grow = (size_t)(row0 + m*16 + lg*4 + r);
        ab[grow*HH + col] = pk_bf16(av, bv);
        A4 *= av; B4 = av*B4 + bv;
      }
      #pragma unroll
      for (int off = 1; off < 4; off <<= 1) {
        float pa = __shfl_up(A4, off*16);
        float pb = __shfl_up(B4, off*16);
        float na = pa*A4, nb = A4*pb + B4;
        if (lg >= off) { A4 = na; B4 = nb; }
      }
      At[m] = __shfl(A4, 48 + lr);
      Bt[m] = __shfl(B4, 48 + lr);
    }
    if (lane < 16) {
      float Ac = At[0]*At[1];
      float Bc = At[1]*Bt[0] + Bt[1];
      size_t sidx = ((size_t)b*128 + col)*256 + c;   // transposed
      AsT[sidx] = Ac;
      BsT[sidx] = Bc;
    }
  }
}

// K3: wave-parallel scan [green text]
__global__ __launch_bounds__(256) void scan2_kernel(
    const float* __restrict__ AsT, const float* __restrict__ BsT, float* __restrict__ carT)
{
  int wid = threadIdx.x >> 6, lane = threadIdx.x & 63;
  int s = blockIdx.x*4 + wid;     // 0..1023 = b*128+d
  float4 Av = ((const float4*)(AsT + (size_t)s*256))[lane];
  float4 Bv = ((const float4*)(BsT + (size_t)s*256))[lane];
  float Ai = Av.x, Bi = Bv.x;
  Bi = Av.y*Bi + Bv.y; Ai = Av.y*Ai;
  Bi = Av.z*Bi + Bv.z; Ai = Av.z*Ai;
  Bi = Av.w*Bi + Bv.w; Ai = Av.w*Ai;
  #pragma unroll
  for (int off = 1; off < 64; off <<= 1) {
    float pA = __shfl_up(Ai, off);
    float pB = __shfl_up(Bi, off);
    if (lane >= off) { Bi = Ai*pB + Bi; Ai = Ai*pA; }
  }
  float exB = __shfl_up(Bi, 1);
  if (lane == 0) exB = 0.f;
  float run = exB;
  float4 cv;
  cv.x = run; run = Av.x*run + Bv.x;
  cv.y = run; run = Av.y*run + Bv.y;
  cv.z = run; run = Av.z*run + Bv.z;
  cv.w = run;
  ((float4*)(carT + (size_t)s*256))[lane] = cv;
}

// K4: apply recurrence + fused LN -> h (bf16). [round-15 text, recurrence/LN split:
// pass A = serial 2-FMA chain only (saves 8 h snapshots), pass B = 8 independent LN
// reductions with full ILP. Same FP ops & per-value order => bit-identical.]
__global__ __launch_bounds__(256) void apply_kernel(
    const unsigned* __restrict__ ab, const float* __restrict__ carT,
    const float* __restrict__ g, const float* __restrict__ be,
    unsigned short* __restrict__ hout)
{
  int tid = threadIdx.x, wid = tid >> 6, lane = tid & 63;
  int chunk = blockIdx.x*4 + wid;
  int b = chunk >> 8, c = chunk & 255;
  float2 hc;
  hc.x = carT[((size_t)b*128 + 2*lane    )*256 + c];
  hc.y = carT[((size_t)b*128 + 2*lane + 1)*256 + c];
  float2 gam = ((const float2*)g)[lane];
  float2 bet = ((const float2*)be)[lane];
  size_t rowbase = (size_t)chunk*CHUNK;
  for (int gq = 0; gq < 4; ++gq) {
    uint2 v[8];
    #pragma unroll
    for (int j = 0; j < 8; ++j)
      v[j] = ((const uint2*)(ab + (rowbase + gq*8 + j)*HH))[lane];
    // pass A: recurrence only (true serial chain = 2 FMAs/step)
    float hx[8], hy[8];
    #pragma unroll
    for (int j = 0; j < 8; ++j) {
      float ax = bf2f(v[j].x & 0xffffu), bx = bf2f(v[j].x >> 16);
      float ay = bf2f(v[j].y & 0xffffu), by = bf2f(v[j].y >> 16);
      hc.x = ax*hc.x + bx;
      hc.y = ay*hc.y + by;
      hx[j] = hc.x; hy[j] = hc.y;
    }
    // pass B: independent LN reductions (full ILP)
    #pragma unroll
    for (int j = 0; j < 8; ++j) {
      float s = hx[j] + hy[j], q = hx[j]*hx[j] + hy[j]*hy[j];
      #pragma unroll
      for (int m = 1; m < 64; m <<= 1) { s += __shfl_xor(s, m); q += __shfl_xor(q, m); }
      float mu = s * (1.f/128.f);
      float var = q * (1.f/128.f) - mu*mu;
      float rs = rsqrtf(var + 1e-5f);
      unsigned o = pk_bf16((hx[j]-mu)*rs*gam.x + bet.x, (hy[j]-mu)*rs*gam.y + bet.y);
      ((unsigned*)hout)[(rowbase + gq*8 + j)*64 + lane] = o;
    }
  }
}

// K5 (layer 3): apply + LN -> LDS tile -> proj MFMA + softplus -> out
// [R13/R15 green text + recurrence/LN split]
__global__ __launch_bounds__(256) void apply_proj_kernel(
    const unsigned* __restrict__ ab, const float* __restrict__ carT,
    const float* __restrict__ g, const float* __restrict__ be,
    const unsigned short* __restrict__ wt_p, const float* __restrict__ pb,
    float* __restrict__ out)
{
  __shared__ short8 wlds[1024];        // 16 KB proj weights
  __shared__ unsigned hlds[4*2048];    // 32 KB per-wave h tiles
  int tid = threadIdx.x, wid = tid >> 6, lane = tid & 63;
  const short8* wsrc = (const short8*)wt_p;
  #pragma unroll
  for (int i = 0; i < 4; ++i) wlds[i*256 + tid] = wsrc[i*256 + tid];

  int chunk = blockIdx.x*4 + wid;
  int b = chunk >> 8, c = chunk & 255;
  float2 hc;
  hc.x = carT[((size_t)b*128 + 2*lane    )*256 + c];
  hc.y = carT[((size_t)b*128 + 2*lane + 1)*256 + c];
  float2 gam = ((const float2*)g)[lane];
  float2 bet = ((const float2*)be)[lane];
  size_t rowbase = (size_t)chunk*CHUNK;
  unsigned* myh = hlds + wid*2048;

  for (int gq = 0; gq < 4; ++gq) {
    uint2 v[8];
    #pragma unroll
    for (int j = 0; j < 8; ++j)
      v[j] = ((const uint2*)(ab + (rowbase + gq*8 + j)*HH))[lane];
    float hx[8], hy[8];
    #pragma unroll
    for (int j = 0; j < 8; ++j) {
      float ax = bf2f(v[j].x & 0xffffu), bx = bf2f(v[j].x >> 16);
      float ay = bf2f(v[j].y & 0xffffu), by = bf2f(v[j].y >> 16);
      hc.x = ax*hc.x + bx;
      hc.y = ay*hc.y + by;
      hx[j] = hc.x; hy[j] = hc.y;
    }
    #pragma unroll
    for (int j = 0; j < 8; ++j) {
      float s = hx[j] + hy[j], q = hx[j]*hx[j] + hy[j]*hy[j];
      #pragma unroll
      for (int m2 = 1; m2 < 64; m2 <<= 1) { s += __shfl_xor(s, m2); q += __shfl_xor(q, m2); }
      float mu = s * (1.f/128.f);
      float var = q * (1.f/128.f) - mu*mu;
      float rs = rsqrtf(var + 1e-5f);
      unsigned o = pk_bf16((hx[j]-mu)*rs*gam.x + bet.x, (hy[j]-mu)*rs*gam.y + bet.y);
      int t = gq*8 + j;
      myh[(t*64 + lane) ^ ((t & 7) << 2)] = o;
    }
  }
  __syncthreads();

  int lr = lane & 15, lg = lane >> 4;
  int sx = (lane & 7) << 4;
  short8 af[2][4];
  #pragma unroll
  for (int m = 0; m < 2; ++m)
    #pragma unroll
    for (int s = 0; s < 4; ++s) {
      int row = m*16 + lr;
      af[m][s] = *(const short8*)(myh + (((row*64) + s*16 + lg*4) ^ ((row & 7) << 2)));
    }

  const char* wbase = (const char*)wlds;
  f32x4 acc[2][4];
  #pragma unroll
  for (int m = 0; m < 2; ++m)
    #pragma unroll
    for (int np = 0; np < 4; ++np) acc[m][np] = (f32x4){0.f,0.f,0.f,0.f};

  #pragma unroll
  for (int np = 0; np < 4; ++np) {
    int col = np*16 + lr;
    #pragma unroll
    for (int s = 0; s < 4; ++s) {
      short8 bh = *(const short8*)(wbase + ((col*256 + s*64 + lg*16) ^ sx));
      #pragma unroll
      for (int m = 0; m < 2; ++m)
        acc[m][np] = __builtin_amdgcn_mfma_f32_16x16x32_bf16(af[m][s], bh, acc[m][np], 0, 0, 0);
    }
  }

  #pragma unroll
  for (int np = 0; np < 4; ++np) {
    int col = np*16 + lr;
    bool act = col < 50;
    float bias = act ? pb[col] : 0.f;
    #pragma unroll
    for (int m = 0; m < 2; ++m)
      #pragma unroll
      for (int r = 0; r < 4; ++r) {
        float v = acc[m][np][r] + bias;
        float sp = fmaxf(v, 0.f) + log1pf(__expf(-fabsf(v)));
        if (act) out[(rowbase + m*16 + lg*4 + r)*50 + col] = sp;
      }
  }
}

extern "C" void kernel_launch(void* const* d_in, const int* in_sizes, int n_in,
                              void* d_out, int out_size, void* d_ws, size_t ws_size,
                              hipStream_t stream) {
  const float* x    = (const float*)d_in[0];
  const float* ew   = (const float*)d_in[1];
  const float* eb   = (const float*)d_in[2];
  const float* ln0g = (const float*)d_in[3];
  const float* ln0b = (const float*)d_in[4];
  const float* pw   = (const float*)d_in[5];
  const float* pb   = (const float*)d_in[6];
  float* out = (float*)d_out;

  size_t nBT  = (size_t)BB*TT*HH;
  size_t nSum = (size_t)BB*NC*HH;
  unsigned short* h  = (unsigned short*)d_ws;
  unsigned*       ab = (unsigned*)(h + nBT);
  float* AsT  = (float*)(ab + nBT);
  float* BsT  = AsT + nSum;
  float* carT = BsT + nSum;
  unsigned short* wt   = (unsigned short*)(carT + nSum);
  unsigned short* wt_e = wt + 3*32768;
  unsigned short* wt_p = wt_e + 8192;

  prep_kernel<<<448, 256, 0, stream>>>((const float*)d_in[7], (const float*)d_in[11],
                                       (const float*)d_in[15], ew, pw, wt, wt_e, wt_p);
  embed_mfma_kernel<<<(BB*TT)/128, 256, 0, stream>>>(x, wt_e, eb, ln0g, ln0b, h);

  for (int l = 0; l < 3; ++l) {
    const float* gb = (const float*)d_in[8 + 4*l];
    const float* lg = (const float*)d_in[9 + 4*l];
    const float* lb = (const float*)d_in[10 + 4*l];
    gru_mm_kernel<<<(BB*NC)/4, 256, 0, stream>>>(h, wt + (size_t)l*32768, gb, ab, AsT, BsT);
    scan2_kernel<<<256, 256, 0, stream>>>(AsT, BsT, carT);
    if (l < 2) {
      apply_kernel<<<(BB*NC)/4, 256, 0, stream>>>(ab, carT, lg, lb, h);
    } else {
      apply_proj_kernel<<<(BB*NC)/4, 256, 0, stream>>>(ab, carT, lg, lb, wt_p, pb, out);
    }
  }
}

// Round 17
// 132.927 us; speedup vs baseline: 1.1489x; 1.0451x over previous
//
#include <hip/hip_runtime.h>
#include <math.h>

#define BB 8
#define TT 8192
#define XX 64
#define HH 128
#define CHUNK 32
#define NC (TT/CHUNK)

typedef __attribute__((ext_vector_type(8))) short short8;
typedef __attribute__((ext_vector_type(4))) float f32x4;

// fast sigmoid: v_rcp_f32 (~1 ulp) instead of IEEE div sequence.
__device__ __forceinline__ float sigm(float x){
  return __builtin_amdgcn_rcpf(1.0f + __expf(-x));
}
__device__ __forceinline__ unsigned short f2bf(float f){
  unsigned u = __float_as_uint(f);
  return (unsigned short)((u + 0x7fffu + ((u>>16)&1u)) >> 16);
}
__device__ __forceinline__ float bf2f(unsigned b){ return __uint_as_float(b << 16); }
// single-instruction pack: lo -> bits[15:0], hi -> bits[31:16] (RNE).
__device__ __forceinline__ unsigned pk_bf16(float lo, float hi){
  unsigned r;
  asm("v_cvt_pk_bf16_f32 %0, %1, %2" : "=v"(r) : "v"(lo), "v"(hi));
  return r;
}

// P0: build bf16 weight tables, pre-swizzled (byte ^= (col&7)<<4).
__global__ __launch_bounds__(256) void prep_kernel(
    const float* __restrict__ w1, const float* __restrict__ w2, const float* __restrict__ w3,
    const float* __restrict__ ew, const float* __restrict__ pw,
    unsigned short* __restrict__ wt, unsigned short* __restrict__ wt_e, unsigned short* __restrict__ wt_p)
{
  int idx = blockIdx.x*256 + threadIdx.x;
  if (idx < 98304) {
    int l = idx >> 15;
    int e = idx & 32767;
    int k = e >> 8;
    int col = e & 255;
    const float* w = (l==0) ? w1 : ((l==1) ? w2 : w3);
    float v = w[e];
    unsigned byte = ((unsigned)col*128u + (unsigned)k)*2u;
    byte ^= (unsigned)((col & 7) << 4);
    wt[(size_t)l*32768 + (byte >> 1)] = f2bf(v);
  } else if (idx < 106496) {
    int e = idx - 98304;
    int col = e >> 6, k = e & 63;
    float v = ew[k*HH + col];
    unsigned byte = ((unsigned)e*2u) ^ (unsigned)((col & 7) << 4);
    wt_e[byte >> 1] = f2bf(v);
  } else if (idx < 114688) {
    int e = idx - 106496;
    int col = e >> 7, k = e & 127;
    float v = (col < 50) ? pw[k*50 + col] : 0.f;
    unsigned byte = ((unsigned)e*2u) ^ (unsigned)((col & 7) << 4);
    wt_p[byte >> 1] = f2bf(v);
  }
}

// K1: embed (64->128) MFMA + leaky_relu + LN0 -> h (bf16)  [green text]
__global__ __launch_bounds__(256) void embed_mfma_kernel(
    const float* __restrict__ x, const unsigned short* __restrict__ wt_e,
    const float* __restrict__ eb, const float* __restrict__ g, const float* __restrict__ be,
    unsigned short* __restrict__ hout)
{
  __shared__ short8 wlds[1024];
  int tid = threadIdx.x;
  const short8* wsrc = (const short8*)wt_e;
  #pragma unroll
  for (int i = 0; i < 4; ++i) wlds[i*256 + tid] = wsrc[i*256 + tid];

  int wid = tid >> 6, lane = tid & 63;
  int lr = lane & 15, lg = lane >> 4;
  int sx = (lane & 7) << 4;
  long row0 = (long)(blockIdx.x*4 + wid)*32;

  short8 af[2][2];
  #pragma unroll
  for (int m = 0; m < 2; ++m)
    #pragma unroll
    for (int s = 0; s < 2; ++s) {
      const float* xp = x + (row0 + m*16 + lr)*XX + s*32 + lg*8;
      float4 u0 = *(const float4*)xp;
      float4 u1 = *(const float4*)(xp + 4);
      uint4 t;
      t.x = pk_bf16(u0.x, u0.y); t.y = pk_bf16(u0.z, u0.w);
      t.z = pk_bf16(u1.x, u1.y); t.w = pk_bf16(u1.z, u1.w);
      af[m][s] = *reinterpret_cast<short8*>(&t);
    }
  __syncthreads();

  const char* wbase = (const char*)wlds;
  f32x4 acc[2][8];
  #pragma unroll
  for (int m = 0; m < 2; ++m)
    #pragma unroll
    for (int np = 0; np < 8; ++np) acc[m][np] = (f32x4){0.f,0.f,0.f,0.f};

  #pragma unroll
  for (int np = 0; np < 8; ++np) {
    int col = np*16 + lr;
    #pragma unroll
    for (int s = 0; s < 2; ++s) {
      short8 bh = *(const short8*)(wbase + ((col*128 + s*64 + lg*16) ^ sx));
      #pragma unroll
      for (int m = 0; m < 2; ++m)
        acc[m][np] = __builtin_amdgcn_mfma_f32_16x16x32_bf16(af[m][s], bh, acc[m][np], 0, 0, 0);
    }
  }

  float gamv[8], betv[8], biasv[8];
  #pragma unroll
  for (int np = 0; np < 8; ++np) {
    int col = np*16 + lr;
    gamv[np] = g[col]; betv[np] = be[col]; biasv[np] = eb[col];
  }

  #pragma unroll
  for (int m = 0; m < 2; ++m) {
    float s4[4], q4[4];
    #pragma unroll
    for (int r = 0; r < 4; ++r) { s4[r] = 0.f; q4[r] = 0.f; }
    #pragma unroll
    for (int np = 0; np < 8; ++np)
      #pragma unroll
      for (int r = 0; r < 4; ++r) {
        float v = acc[m][np][r] + biasv[np];
        v = v > 0.f ? v : 0.01f*v;
        acc[m][np][r] = v;
        s4[r] += v; q4[r] += v*v;
      }
    #pragma unroll
    for (int off = 1; off < 16; off <<= 1)
      #pragma unroll
      for (int r = 0; r < 4; ++r) {
        s4[r] += __shfl_xor(s4[r], off);
        q4[r] += __shfl_xor(q4[r], off);
      }
    #pragma unroll
    for (int r = 0; r < 4; ++r) {
      float mu = s4[r] * (1.f/128.f);
      float var = q4[r] * (1.f/128.f) - mu*mu;
      float rs = rsqrtf(var + 1e-5f);
      long row = row0 + m*16 + lg*4 + r;
      #pragma unroll
      for (int np = 0; np < 8; ++np)
        hout[row*HH + np*16 + lr] = f2bf((acc[m][np][r]-mu)*rs*gamv[np] + betv[np]);
    }
  }
}

// K2: MFMA minGRU matmul [round-15 green text]
__global__ __launch_bounds__(256) void gru_mm_kernel(
    const unsigned short* __restrict__ h, const unsigned short* __restrict__ wt,
    const float* __restrict__ bias,
    unsigned* __restrict__ ab, float* __restrict__ AsT, float* __restrict__ BsT)
{
  __shared__ short8 wlds[4096];   // 64 KB
  int tid = threadIdx.x;
  int wid = tid >> 6, lane = tid & 63;
  int chunk = blockIdx.x*4 + wid;
  int b = chunk >> 8, c = chunk & 255;
  long row0 = (long)b*TT + (long)c*CHUNK;
  int lr = lane & 15, lg = lane >> 4;
  int sx = (lane & 7) << 4;

  short8 af[2][4];
  #pragma unroll
  for (int m = 0; m < 2; ++m)
    #pragma unroll
    for (int s = 0; s < 4; ++s)
      af[m][s] = *(const short8*)(h + (row0 + m*16 + lr)*HH + s*32 + lg*8);

  const short8* wsrc = (const short8*)wt;
  #pragma unroll
  for (int i = 0; i < 16; ++i) wlds[i*256 + tid] = wsrc[i*256 + tid];
  __syncthreads();

  const char* wbase = (const char*)wlds;
  #pragma unroll 2
  for (int np = 0; np < 8; ++np) {
    f32x4 acch[2], accg[2];
    #pragma unroll
    for (int m = 0; m < 2; ++m) { acch[m] = (f32x4){0.f,0.f,0.f,0.f}; accg[m] = (f32x4){0.f,0.f,0.f,0.f}; }
    int rh = np*16 + lr;
    int rg = rh + 128;
    #pragma unroll
    for (int s = 0; s < 4; ++s) {
      short8 bh = *(const short8*)(wbase + ((rh*256 + s*64 + lg*16) ^ sx));
      short8 bg = *(const short8*)(wbase + ((rg*256 + s*64 + lg*16) ^ sx));
      #pragma unroll
      for (int m = 0; m < 2; ++m) {
        acch[m] = __builtin_amdgcn_mfma_f32_16x16x32_bf16(af[m][s], bh, acch[m], 0, 0, 0);
        accg[m] = __builtin_amdgcn_mfma_f32_16x16x32_bf16(af[m][s], bg, accg[m], 0, 0, 0);
      }
    }
    int col = np*16 + lr;
    float bh0 = bias[col], bg0 = bias[HH + col];
    float At[2], Bt[2];
    #pragma unroll
    for (int m = 0; m < 2; ++m) {
      float A4 = 1.f, B4 = 0.f;
      #pragma unroll
      for (int r = 0; r < 4; ++r) {
        float hid = acch[m][r] + bh0;
        float z = sigm(accg[m][r] + bg0);
        float gv = hid >= 0.f ? hid + 0.5f : sigm(hid);
        float av = 1.f - z, bv = z*gv;
        size_t grow = (size_t)(row0 + m*16 + lg*4 + r);
        ab[grow*HH + col] = pk_bf16(av, bv);
        A4 *= av; B4 = av*B4 + bv;
      }
      #pragma unroll
      for (int off = 1; off < 4; off <<= 1) {
        float pa = __shfl_up(A4, off*16);
        float pb = __shfl_up(B4, off*16);
        float na = pa*A4, nb = A4*pb + B4;
        if (lg >= off) { A4 = na; B4 = nb; }
      }
      At[m] = __shfl(A4, 48 + lr);
      Bt[m] = __shfl(B4, 48 + lr);
    }
    if (lane < 16) {
      float Ac = At[0]*At[1];
      float Bc = At[1]*Bt[0] + Bt[1];
      size_t sidx = ((size_t)b*128 + col)*256 + c;   // transposed
      AsT[sidx] = Ac;
      BsT[sidx] = Bc;
    }
  }
}

// K3: wave-parallel scan [green text]
__global__ __launch_bounds__(256) void scan2_kernel(
    const float* __restrict__ AsT, const float* __restrict__ BsT, float* __restrict__ carT)
{
  int wid = threadIdx.x >> 6, lane = threadIdx.x & 63;
  int s = blockIdx.x*4 + wid;     // 0..1023 = b*128+d
  float4 Av = ((const float4*)(AsT + (size_t)s*256))[lane];
  float4 Bv = ((const float4*)(BsT + (size_t)s*256))[lane];
  float Ai = Av.x, Bi = Bv.x;
  Bi = Av.y*Bi + Bv.y; Ai = Av.y*Ai;
  Bi = Av.z*Bi + Bv.z; Ai = Av.z*Ai;
  Bi = Av.w*Bi + Bv.w; Ai = Av.w*Ai;
  #pragma unroll
  for (int off = 1; off < 64; off <<= 1) {
    float pA = __shfl_up(Ai, off);
    float pB = __shfl_up(Bi, off);
    if (lane >= off) { Bi = Ai*pB + Bi; Ai = Ai*pA; }
  }
  float exB = __shfl_up(Bi, 1);
  if (lane == 0) exB = 0.f;
  float run = exB;
  float4 cv;
  cv.x = run; run = Av.x*run + Bv.x;
  cv.y = run; run = Av.y*run + Bv.y;
  cv.z = run; run = Av.z*run + Bv.z;
  cv.w = run;
  ((float4*)(carT + (size_t)s*256))[lane] = cv;
}

// K4: apply recurrence + fused LN -> h (bf16). HALF-WAVE restructure: 32-lane group
// owns one chunk, 4 channels/lane -> uint4 loads (16B/lane), uint2 stores, 5-level
// LN butterfly confined to the half-wave. LN summation tree differs from R15 by
// ~1ulp f32 (4-wide lane-local sum) -- under bf16 granularity.
__global__ __launch_bounds__(256) void apply_kernel(
    const unsigned* __restrict__ ab, const float* __restrict__ carT,
    const float* __restrict__ g, const float* __restrict__ be,
    unsigned short* __restrict__ hout)
{
  int tid = threadIdx.x;
  int hw = tid >> 5;          // half-wave id 0..7
  int l32 = tid & 31;         // lane within half-wave
  int chunk = blockIdx.x*8 + hw;
  int b = chunk >> 8, c = chunk & 255;
  float4 hc;
  hc.x = carT[((size_t)b*128 + 4*l32    )*256 + c];
  hc.y = carT[((size_t)b*128 + 4*l32 + 1)*256 + c];
  hc.z = carT[((size_t)b*128 + 4*l32 + 2)*256 + c];
  hc.w = carT[((size_t)b*128 + 4*l32 + 3)*256 + c];
  float4 gam = ((const float4*)g)[l32];
  float4 bet = ((const float4*)be)[l32];
  size_t rowbase = (size_t)chunk*CHUNK;
  for (int gq = 0; gq < 4; ++gq) {
    uint4 v[8];
    #pragma unroll
    for (int j = 0; j < 8; ++j)
      v[j] = ((const uint4*)(ab + (rowbase + gq*8 + j)*HH))[l32];
    float4 hs[8];
    #pragma unroll
    for (int j = 0; j < 8; ++j) {
      hc.x = bf2f(v[j].x & 0xffffu)*hc.x + bf2f(v[j].x >> 16);
      hc.y = bf2f(v[j].y & 0xffffu)*hc.y + bf2f(v[j].y >> 16);
      hc.z = bf2f(v[j].z & 0xffffu)*hc.z + bf2f(v[j].z >> 16);
      hc.w = bf2f(v[j].w & 0xffffu)*hc.w + bf2f(v[j].w >> 16);
      hs[j] = hc;
    }
    #pragma unroll
    for (int j = 0; j < 8; ++j) {
      float s = (hs[j].x + hs[j].y) + (hs[j].z + hs[j].w);
      float q = (hs[j].x*hs[j].x + hs[j].y*hs[j].y) + (hs[j].z*hs[j].z + hs[j].w*hs[j].w);
      #pragma unroll
      for (int m = 1; m < 32; m <<= 1) { s += __shfl_xor(s, m); q += __shfl_xor(q, m); }
      float mu = s * (1.f/128.f);
      float var = q * (1.f/128.f) - mu*mu;
      float rs = rsqrtf(var + 1e-5f);
      uint2 o;
      o.x = pk_bf16((hs[j].x-mu)*rs*gam.x + bet.x, (hs[j].y-mu)*rs*gam.y + bet.y);
      o.y = pk_bf16((hs[j].z-mu)*rs*gam.z + bet.z, (hs[j].w-mu)*rs*gam.w + bet.w);
      ((uint2*)hout)[(rowbase + gq*8 + j)*32 + l32] = o;
    }
  }
}

// K5 (layer 3): apply + LN -> LDS tile -> proj MFMA + softplus -> out [R16 green text]
__global__ __launch_bounds__(256) void apply_proj_kernel(
    const unsigned* __restrict__ ab, const float* __restrict__ carT,
    const float* __restrict__ g, const float* __restrict__ be,
    const unsigned short* __restrict__ wt_p, const float* __restrict__ pb,
    float* __restrict__ out)
{
  __shared__ short8 wlds[1024];        // 16 KB proj weights
  __shared__ unsigned hlds[4*2048];    // 32 KB per-wave h tiles
  int tid = threadIdx.x, wid = tid >> 6, lane = tid & 63;
  const short8* wsrc = (const short8*)wt_p;
  #pragma unroll
  for (int i = 0; i < 4; ++i) wlds[i*256 + tid] = wsrc[i*256 + tid];

  int chunk = blockIdx.x*4 + wid;
  int b = chunk >> 8, c = chunk & 255;
  float2 hc;
  hc.x = carT[((size_t)b*128 + 2*lane    )*256 + c];
  hc.y = carT[((size_t)b*128 + 2*lane + 1)*256 + c];
  float2 gam = ((const float2*)g)[lane];
  float2 bet = ((const float2*)be)[lane];
  size_t rowbase = (size_t)chunk*CHUNK;
  unsigned* myh = hlds + wid*2048;

  for (int gq = 0; gq < 4; ++gq) {
    uint2 v[8];
    #pragma unroll
    for (int j = 0; j < 8; ++j)
      v[j] = ((const uint2*)(ab + (rowbase + gq*8 + j)*HH))[lane];
    float hx[8], hy[8];
    #pragma unroll
    for (int j = 0; j < 8; ++j) {
      float ax = bf2f(v[j].x & 0xffffu), bx = bf2f(v[j].x >> 16);
      float ay = bf2f(v[j].y & 0xffffu), by = bf2f(v[j].y >> 16);
      hc.x = ax*hc.x + bx;
      hc.y = ay*hc.y + by;
      hx[j] = hc.x; hy[j] = hc.y;
    }
    #pragma unroll
    for (int j = 0; j < 8; ++j) {
      float s = hx[j] + hy[j], q = hx[j]*hx[j] + hy[j]*hy[j];
      #pragma unroll
      for (int m2 = 1; m2 < 64; m2 <<= 1) { s += __shfl_xor(s, m2); q += __shfl_xor(q, m2); }
      float mu = s * (1.f/128.f);
      float var = q * (1.f/128.f) - mu*mu;
      float rs = rsqrtf(var + 1e-5f);
      unsigned o = pk_bf16((hx[j]-mu)*rs*gam.x + bet.x, (hy[j]-mu)*rs*gam.y + bet.y);
      int t = gq*8 + j;
      myh[(t*64 + lane) ^ ((t & 7) << 2)] = o;
    }
  }
  __syncthreads();

  int lr = lane & 15, lg = lane >> 4;
  int sx = (lane & 7) << 4;
  short8 af[2][4];
  #pragma unroll
  for (int m = 0; m < 2; ++m)
    #pragma unroll
    for (int s = 0; s < 4; ++s) {
      int row = m*16 + lr;
      af[m][s] = *(const short8*)(myh + (((row*64) + s*16 + lg*4) ^ ((row & 7) << 2)));
    }

  const char* wbase = (const char*)wlds;
  f32x4 acc[2][4];
  #pragma unroll
  for (int m = 0; m < 2; ++m)
    #pragma unroll
    for (int np = 0; np < 4; ++np) acc[m][np] = (f32x4){0.f,0.f,0.f,0.f};

  #pragma unroll
  for (int np = 0; np < 4; ++np) {
    int col = np*16 + lr;
    #pragma unroll
    for (int s = 0; s < 4; ++s) {
      short8 bh = *(const short8*)(wbase + ((col*256 + s*64 + lg*16) ^ sx));
      #pragma unroll
      for (int m = 0; m < 2; ++m)
        acc[m][np] = __builtin_amdgcn_mfma_f32_16x16x32_bf16(af[m][s], bh, acc[m][np], 0, 0, 0);
    }
  }

  #pragma unroll
  for (int np = 0; np < 4; ++np) {
    int col = np*16 + lr;
    bool act = col < 50;
    float bias = act ? pb[col] : 0.f;
    #pragma unroll
    for (int m = 0; m < 2; ++m)
      #pragma unroll
      for (int r = 0; r < 4; ++r) {
        float v = acc[m][np][r] + bias;
        float sp = fmaxf(v, 0.f) + log1pf(__expf(-fabsf(v)));
        if (act) out[(rowbase + m*16 + lg*4 + r)*50 + col] = sp;
      }
  }
}

extern "C" void kernel_launch(void* const* d_in, const int* in_sizes, int n_in,
                              void* d_out, int out_size, void* d_ws, size_t ws_size,
                              hipStream_t stream) {
  const float* x    = (const float*)d_in[0];
  const float* ew   = (const float*)d_in[1];
  const float* eb   = (const float*)d_in[2];
  const float* ln0g = (const float*)d_in[3];
  const float* ln0b = (const float*)d_in[4];
  const float* pw   = (const float*)d_in[5];
  const float* pb   = (const float*)d_in[6];
  float* out = (float*)d_out;

  size_t nBT  = (size_t)BB*TT*HH;
  size_t nSum = (size_t)BB*NC*HH;
  unsigned short* h  = (unsigned short*)d_ws;
  unsigned*       ab = (unsigned*)(h + nBT);
  float* AsT  = (float*)(ab + nBT);
  float* BsT  = AsT + nSum;
  float* carT = BsT + nSum;
  unsigned short* wt   = (unsigned short*)(carT + nSum);
  unsigned short* wt_e = wt + 3*32768;
  unsigned short* wt_p = wt_e + 8192;

  prep_kernel<<<448, 256, 0, stream>>>((const float*)d_in[7], (const float*)d_in[11],
                                       (const float*)d_in[15], ew, pw, wt, wt_e, wt_p);
  embed_mfma_kernel<<<(BB*TT)/128, 256, 0, stream>>>(x, wt_e, eb, ln0g, ln0b, h);

  for (int l = 0; l < 3; ++l) {
    const float* gb = (const float*)d_in[8 + 4*l];
    const float* lg = (const float*)d_in[9 + 4*l];
    const float* lb = (const float*)d_in[10 + 4*l];
    gru_mm_kernel<<<(BB*NC)/4, 256, 0, stream>>>(h, wt + (size_t)l*32768, gb, ab, AsT, BsT);
    scan2_kernel<<<256, 256, 0, stream>>>(AsT, BsT, carT);
    if (l < 2) {
      apply_kernel<<<(BB*NC)/8, 256, 0, stream>>>(ab, carT, lg, lb, h);
    } else {
      apply_proj_kernel<<<(BB*NC)/4, 256, 0, stream>>>(ab, carT, lg, lb, wt_p, pb, out);
    }
  }
}

// Round 18
// 132.420 us; speedup vs baseline: 1.1533x; 1.0038x over previous
//
#include <hip/hip_runtime.h>
#include <math.h>

#define BB 8
#define TT 8192
#define XX 64
#define HH 128
#define CHUNK 32
#define NC (TT/CHUNK)

typedef __attribute__((ext_vector_type(8))) short short8;
typedef __attribute__((ext_vector_type(4))) float f32x4;

// fast sigmoid: v_rcp_f32 (~1 ulp) instead of IEEE div sequence.
__device__ __forceinline__ float sigm(float x){
  return __builtin_amdgcn_rcpf(1.0f + __expf(-x));
}
__device__ __forceinline__ unsigned short f2bf(float f){
  unsigned u = __float_as_uint(f);
  return (unsigned short)((u + 0x7fffu + ((u>>16)&1u)) >> 16);
}
__device__ __forceinline__ float bf2f(unsigned b){ return __uint_as_float(b << 16); }
// single-instruction pack: lo -> bits[15:0], hi -> bits[31:16] (RNE).
__device__ __forceinline__ unsigned pk_bf16(float lo, float hi){
  unsigned r;
  asm("v_cvt_pk_bf16_f32 %0, %1, %2" : "=v"(r) : "v"(lo), "v"(hi));
  return r;
}

// P0: build bf16 weight tables, pre-swizzled (byte ^= (col&7)<<4).
__global__ __launch_bounds__(256) void prep_kernel(
    const float* __restrict__ w1, const float* __restrict__ w2, const float* __restrict__ w3,
    const float* __restrict__ ew, const float* __restrict__ pw,
    unsigned short* __restrict__ wt, unsigned short* __restrict__ wt_e, unsigned short* __restrict__ wt_p)
{
  int idx = blockIdx.x*256 + threadIdx.x;
  if (idx < 98304) {
    int l = idx >> 15;
    int e = idx & 32767;
    int k = e >> 8;
    int col = e & 255;
    const float* w = (l==0) ? w1 : ((l==1) ? w2 : w3);
    float v = w[e];
    unsigned byte = ((unsigned)col*128u + (unsigned)k)*2u;
    byte ^= (unsigned)((col & 7) << 4);
    wt[(size_t)l*32768 + (byte >> 1)] = f2bf(v);
  } else if (idx < 106496) {
    int e = idx - 98304;
    int col = e >> 6, k = e & 63;
    float v = ew[k*HH + col];
    unsigned byte = ((unsigned)e*2u) ^ (unsigned)((col & 7) << 4);
    wt_e[byte >> 1] = f2bf(v);
  } else if (idx < 114688) {
    int e = idx - 106496;
    int col = e >> 7, k = e & 127;
    float v = (col < 50) ? pw[k*50 + col] : 0.f;
    unsigned byte = ((unsigned)e*2u) ^ (unsigned)((col & 7) << 4);
    wt_p[byte >> 1] = f2bf(v);
  }
}

// K1: embed (64->128) MFMA + leaky_relu + LN0 -> h (bf16)  [green text]
__global__ __launch_bounds__(256) void embed_mfma_kernel(
    const float* __restrict__ x, const unsigned short* __restrict__ wt_e,
    const float* __restrict__ eb, const float* __restrict__ g, const float* __restrict__ be,
    unsigned short* __restrict__ hout)
{
  __shared__ short8 wlds[1024];
  int tid = threadIdx.x;
  const short8* wsrc = (const short8*)wt_e;
  #pragma unroll
  for (int i = 0; i < 4; ++i) wlds[i*256 + tid] = wsrc[i*256 + tid];

  int wid = tid >> 6, lane = tid & 63;
  int lr = lane & 15, lg = lane >> 4;
  int sx = (lane & 7) << 4;
  long row0 = (long)(blockIdx.x*4 + wid)*32;

  short8 af[2][2];
  #pragma unroll
  for (int m = 0; m < 2; ++m)
    #pragma unroll
    for (int s = 0; s < 2; ++s) {
      const float* xp = x + (row0 + m*16 + lr)*XX + s*32 + lg*8;
      float4 u0 = *(const float4*)xp;
      float4 u1 = *(const float4*)(xp + 4);
      uint4 t;
      t.x = pk_bf16(u0.x, u0.y); t.y = pk_bf16(u0.z, u0.w);
      t.z = pk_bf16(u1.x, u1.y); t.w = pk_bf16(u1.z, u1.w);
      af[m][s] = *reinterpret_cast<short8*>(&t);
    }
  __syncthreads();

  const char* wbase = (const char*)wlds;
  f32x4 acc[2][8];
  #pragma unroll
  for (int m = 0; m < 2; ++m)
    #pragma unroll
    for (int np = 0; np < 8; ++np) acc[m][np] = (f32x4){0.f,0.f,0.f,0.f};

  #pragma unroll
  for (int np = 0; np < 8; ++np) {
    int col = np*16 + lr;
    #pragma unroll
    for (int s = 0; s < 2; ++s) {
      short8 bh = *(const short8*)(wbase + ((col*128 + s*64 + lg*16) ^ sx));
      #pragma unroll
      for (int m = 0; m < 2; ++m)
        acc[m][np] = __builtin_amdgcn_mfma_f32_16x16x32_bf16(af[m][s], bh, acc[m][np], 0, 0, 0);
    }
  }

  float gamv[8], betv[8], biasv[8];
  #pragma unroll
  for (int np = 0; np < 8; ++np) {
    int col = np*16 + lr;
    gamv[np] = g[col]; betv[np] = be[col]; biasv[np] = eb[col];
  }

  #pragma unroll
  for (int m = 0; m < 2; ++m) {
    float s4[4], q4[4];
    #pragma unroll
    for (int r = 0; r < 4; ++r) { s4[r] = 0.f; q4[r] = 0.f; }
    #pragma unroll
    for (int np = 0; np < 8; ++np)
      #pragma unroll
      for (int r = 0; r < 4; ++r) {
        float v = acc[m][np][r] + biasv[np];
        v = v > 0.f ? v : 0.01f*v;
        acc[m][np][r] = v;
        s4[r] += v; q4[r] += v*v;
      }
    #pragma unroll
    for (int off = 1; off < 16; off <<= 1)
      #pragma unroll
      for (int r = 0; r < 4; ++r) {
        s4[r] += __shfl_xor(s4[r], off);
        q4[r] += __shfl_xor(q4[r], off);
      }
    #pragma unroll
    for (int r = 0; r < 4; ++r) {
      float mu = s4[r] * (1.f/128.f);
      float var = q4[r] * (1.f/128.f) - mu*mu;
      float rs = rsqrtf(var + 1e-5f);
      long row = row0 + m*16 + lg*4 + r;
      #pragma unroll
      for (int np = 0; np < 8; ++np)
        hout[row*HH + np*16 + lr] = f2bf((acc[m][np][r]-mu)*rs*gamv[np] + betv[np]);
    }
  }
}

// K2: MFMA minGRU matmul [round-15 green numerics]. ab re-laid-out as
// ab4[chunk][tg=row/4][col][r=row%4]: each thread's 4 packed values per (m,np)
// become ONE uint4 store (64 scattered dwords -> 16 vector stores; 16 lanes x
// 16B = 256B contiguous segments). Values bit-identical; layout-only change.
__global__ __launch_bounds__(256) void gru_mm_kernel(
    const unsigned short* __restrict__ h, const unsigned short* __restrict__ wt,
    const float* __restrict__ bias,
    unsigned* __restrict__ ab, float* __restrict__ AsT, float* __restrict__ BsT)
{
  __shared__ short8 wlds[4096];   // 64 KB
  int tid = threadIdx.x;
  int wid = tid >> 6, lane = tid & 63;
  int chunk = blockIdx.x*4 + wid;
  int b = chunk >> 8, c = chunk & 255;
  long row0 = (long)b*TT + (long)c*CHUNK;
  int lr = lane & 15, lg = lane >> 4;
  int sx = (lane & 7) << 4;

  short8 af[2][4];
  #pragma unroll
  for (int m = 0; m < 2; ++m)
    #pragma unroll
    for (int s = 0; s < 4; ++s)
      af[m][s] = *(const short8*)(h + (row0 + m*16 + lr)*HH + s*32 + lg*8);

  const short8* wsrc = (const short8*)wt;
  #pragma unroll
  for (int i = 0; i < 16; ++i) wlds[i*256 + tid] = wsrc[i*256 + tid];
  __syncthreads();

  const char* wbase = (const char*)wlds;
  #pragma unroll 2
  for (int np = 0; np < 8; ++np) {
    f32x4 acch[2], accg[2];
    #pragma unroll
    for (int m = 0; m < 2; ++m) { acch[m] = (f32x4){0.f,0.f,0.f,0.f}; accg[m] = (f32x4){0.f,0.f,0.f,0.f}; }
    int rh = np*16 + lr;
    int rg = rh + 128;
    #pragma unroll
    for (int s = 0; s < 4; ++s) {
      short8 bh = *(const short8*)(wbase + ((rh*256 + s*64 + lg*16) ^ sx));
      short8 bg = *(const short8*)(wbase + ((rg*256 + s*64 + lg*16) ^ sx));
      #pragma unroll
      for (int m = 0; m < 2; ++m) {
        acch[m] = __builtin_amdgcn_mfma_f32_16x16x32_bf16(af[m][s], bh, acch[m], 0, 0, 0);
        accg[m] = __builtin_amdgcn_mfma_f32_16x16x32_bf16(af[m][s], bg, accg[m], 0, 0, 0);
      }
    }
    int col = np*16 + lr;
    float bh0 = bias[col], bg0 = bias[HH + col];
    float At[2], Bt[2];
    #pragma unroll
    for (int m = 0; m < 2; ++m) {
      float A4 = 1.f, B4 = 0.f;
      unsigned pk4[4];
      #pragma unroll
      for (int r = 0; r < 4; ++r) {
        float hid = acch[m][r] + bh0;
        float z = sigm(accg[m][r] + bg0);
        float gv = hid >= 0.f ? hid + 0.5f : sigm(hid);
        float av = 1.f - z, bv = z*gv;
        pk4[r] = pk_bf16(av, bv);
        A4 *= av; B4 = av*B4 + bv;
      }
      uint4 u; u.x = pk4[0]; u.y = pk4[1]; u.z = pk4[2]; u.w = pk4[3];
      *(uint4*)(ab + (size_t)chunk*4096 + (m*4 + lg)*512 + col*4) = u;
      #pragma unroll
      for (int off = 1; off < 4; off <<= 1) {
        float pa = __shfl_up(A4, off*16);
        float pb = __shfl_up(B4, off*16);
        float na = pa*A4, nb = A4*pb + B4;
        if (lg >= off) { A4 = na; B4 = nb; }
      }
      At[m] = __shfl(A4, 48 + lr);
      Bt[m] = __shfl(B4, 48 + lr);
    }
    if (lane < 16) {
      float Ac = At[0]*At[1];
      float Bc = At[1]*Bt[0] + Bt[1];
      size_t sidx = ((size_t)b*128 + col)*256 + c;   // transposed
      AsT[sidx] = Ac;
      BsT[sidx] = Bc;
    }
  }
}

// K3: wave-parallel scan [green text]
__global__ __launch_bounds__(256) void scan2_kernel(
    const float* __restrict__ AsT, const float* __restrict__ BsT, float* __restrict__ carT)
{
  int wid = threadIdx.x >> 6, lane = threadIdx.x & 63;
  int s = blockIdx.x*4 + wid;     // 0..1023 = b*128+d
  float4 Av = ((const float4*)(AsT + (size_t)s*256))[lane];
  float4 Bv = ((const float4*)(BsT + (size_t)s*256))[lane];
  float Ai = Av.x, Bi = Bv.x;
  Bi = Av.y*Bi + Bv.y; Ai = Av.y*Ai;
  Bi = Av.z*Bi + Bv.z; Ai = Av.z*Ai;
  Bi = Av.w*Bi + Bv.w; Ai = Av.w*Ai;
  #pragma unroll
  for (int off = 1; off < 64; off <<= 1) {
    float pA = __shfl_up(Ai, off);
    float pB = __shfl_up(Bi, off);
    if (lane >= off) { Bi = Ai*pB + Bi; Ai = Ai*pA; }
  }
  float exB = __shfl_up(Bi, 1);
  if (lane == 0) exB = 0.f;
  float run = exB;
  float4 cv;
  cv.x = run; run = Av.x*run + Bv.x;
  cv.y = run; run = Av.y*run + Bv.y;
  cv.z = run; run = Av.z*run + Bv.z;
  cv.w = run;
  ((float4*)(carT + (size_t)s*256))[lane] = cv;
}

// recurrence step for 4 channels from packed words
#define APPLY_T4(W0,W1,W2,W3,J) \
  hc.x = bf2f((W0)&0xffffu)*hc.x + bf2f((W0)>>16); \
  hc.y = bf2f((W1)&0xffffu)*hc.y + bf2f((W1)>>16); \
  hc.z = bf2f((W2)&0xffffu)*hc.z + bf2f((W2)>>16); \
  hc.w = bf2f((W3)&0xffffu)*hc.w + bf2f((W3)>>16); \
  hs[J] = hc;

// K4: apply recurrence + fused LN -> h (bf16). Half-wave (4 ch/lane) with ab4
// layout: per tg, lane's 4 uint4 loads cover 64B contiguous; half-wave covers
// a 2KB span. Values bit-identical to R17.
__global__ __launch_bounds__(256) void apply_kernel(
    const unsigned* __restrict__ ab, const float* __restrict__ carT,
    const float* __restrict__ g, const float* __restrict__ be,
    unsigned short* __restrict__ hout)
{
  int tid = threadIdx.x;
  int hw = tid >> 5, l32 = tid & 31;
  int chunk = blockIdx.x*8 + hw;
  int b = chunk >> 8, c = chunk & 255;
  float4 hc;
  hc.x = carT[((size_t)b*128 + 4*l32    )*256 + c];
  hc.y = carT[((size_t)b*128 + 4*l32 + 1)*256 + c];
  hc.z = carT[((size_t)b*128 + 4*l32 + 2)*256 + c];
  hc.w = carT[((size_t)b*128 + 4*l32 + 3)*256 + c];
  float4 gam = ((const float4*)g)[l32];
  float4 bet = ((const float4*)be)[l32];
  size_t rowbase = (size_t)chunk*CHUNK;
  const uint4* abv4 = (const uint4*)ab + (size_t)chunk*1024;
  for (int gq = 0; gq < 4; ++gq) {
    uint4 ch0[2], ch1[2], ch2[2], ch3[2];
    #pragma unroll
    for (int u = 0; u < 2; ++u) {
      const uint4* p = abv4 + (gq*2 + u)*128 + 4*l32;
      ch0[u] = p[0]; ch1[u] = p[1]; ch2[u] = p[2]; ch3[u] = p[3];
    }
    float4 hs[8];
    #pragma unroll
    for (int u = 0; u < 2; ++u) {
      APPLY_T4(ch0[u].x, ch1[u].x, ch2[u].x, ch3[u].x, u*4+0)
      APPLY_T4(ch0[u].y, ch1[u].y, ch2[u].y, ch3[u].y, u*4+1)
      APPLY_T4(ch0[u].z, ch1[u].z, ch2[u].z, ch3[u].z, u*4+2)
      APPLY_T4(ch0[u].w, ch1[u].w, ch2[u].w, ch3[u].w, u*4+3)
    }
    #pragma unroll
    for (int j = 0; j < 8; ++j) {
      float s = (hs[j].x + hs[j].y) + (hs[j].z + hs[j].w);
      float q = (hs[j].x*hs[j].x + hs[j].y*hs[j].y) + (hs[j].z*hs[j].z + hs[j].w*hs[j].w);
      #pragma unroll
      for (int m = 1; m < 32; m <<= 1) { s += __shfl_xor(s, m); q += __shfl_xor(q, m); }
      float mu = s * (1.f/128.f);
      float var = q * (1.f/128.f) - mu*mu;
      float rs = rsqrtf(var + 1e-5f);
      uint2 o;
      o.x = pk_bf16((hs[j].x-mu)*rs*gam.x + bet.x, (hs[j].y-mu)*rs*gam.y + bet.y);
      o.y = pk_bf16((hs[j].z-mu)*rs*gam.z + bet.z, (hs[j].w-mu)*rs*gam.w + bet.w);
      ((uint2*)hout)[(rowbase + gq*8 + j)*32 + l32] = o;
    }
  }
}

// K5 (layer 3): apply + LN -> LDS tile -> proj MFMA + softplus -> out.
// apply phase reads ab4 (2 ch/lane -> 2 uint4 loads per tg). Tile contract
// unchanged from R13-validated form.
__global__ __launch_bounds__(256) void apply_proj_kernel(
    const unsigned* __restrict__ ab, const float* __restrict__ carT,
    const float* __restrict__ g, const float* __restrict__ be,
    const unsigned short* __restrict__ wt_p, const float* __restrict__ pb,
    float* __restrict__ out)
{
  __shared__ short8 wlds[1024];        // 16 KB proj weights
  __shared__ unsigned hlds[4*2048];    // 32 KB per-wave h tiles
  int tid = threadIdx.x, wid = tid >> 6, lane = tid & 63;
  const short8* wsrc = (const short8*)wt_p;
  #pragma unroll
  for (int i = 0; i < 4; ++i) wlds[i*256 + tid] = wsrc[i*256 + tid];

  int chunk = blockIdx.x*4 + wid;
  int b = chunk >> 8, c = chunk & 255;
  float2 hc;
  hc.x = carT[((size_t)b*128 + 2*lane    )*256 + c];
  hc.y = carT[((size_t)b*128 + 2*lane + 1)*256 + c];
  float2 gam = ((const float2*)g)[lane];
  float2 bet = ((const float2*)be)[lane];
  size_t rowbase = (size_t)chunk*CHUNK;
  unsigned* myh = hlds + wid*2048;
  const uint4* abv4 = (const uint4*)ab + (size_t)chunk*1024;

  for (int gq = 0; gq < 4; ++gq) {
    uint4 c0[2], c1[2];
    #pragma unroll
    for (int u = 0; u < 2; ++u) {
      const uint4* p = abv4 + (gq*2 + u)*128 + 2*lane;
      c0[u] = p[0]; c1[u] = p[1];
    }
    float hx[8], hy[8];
    #pragma unroll
    for (int u = 0; u < 2; ++u) {
      hc.x = bf2f(c0[u].x&0xffffu)*hc.x + bf2f(c0[u].x>>16);
      hc.y = bf2f(c1[u].x&0xffffu)*hc.y + bf2f(c1[u].x>>16);
      hx[u*4+0] = hc.x; hy[u*4+0] = hc.y;
      hc.x = bf2f(c0[u].y&0xffffu)*hc.x + bf2f(c0[u].y>>16);
      hc.y = bf2f(c1[u].y&0xffffu)*hc.y + bf2f(c1[u].y>>16);
      hx[u*4+1] = hc.x; hy[u*4+1] = hc.y;
      hc.x = bf2f(c0[u].z&0xffffu)*hc.x + bf2f(c0[u].z>>16);
      hc.y = bf2f(c1[u].z&0xffffu)*hc.y + bf2f(c1[u].z>>16);
      hx[u*4+2] = hc.x; hy[u*4+2] = hc.y;
      hc.x = bf2f(c0[u].w&0xffffu)*hc.x + bf2f(c0[u].w>>16);
      hc.y = bf2f(c1[u].w&0xffffu)*hc.y + bf2f(c1[u].w>>16);
      hx[u*4+3] = hc.x; hy[u*4+3] = hc.y;
    }
    #pragma unroll
    for (int j = 0; j < 8; ++j) {
      float s = hx[j] + hy[j], q = hx[j]*hx[j] + hy[j]*hy[j];
      #pragma unroll
      for (int m2 = 1; m2 < 64; m2 <<= 1) { s += __shfl_xor(s, m2); q += __shfl_xor(q, m2); }
      float mu = s * (1.f/128.f);
      float var = q * (1.f/128.f) - mu*mu;
      float rs = rsqrtf(var + 1e-5f);
      unsigned o = pk_bf16((hx[j]-mu)*rs*gam.x + bet.x, (hy[j]-mu)*rs*gam.y + bet.y);
      int t = gq*8 + j;
      myh[(t*64 + lane) ^ ((t & 7) << 2)] = o;
    }
  }
  __syncthreads();

  int lr = lane & 15, lg = lane >> 4;
  int sx = (lane & 7) << 4;
  short8 af[2][4];
  #pragma unroll
  for (int m = 0; m < 2; ++m)
    #pragma unroll
    for (int s = 0; s < 4; ++s) {
      int row = m*16 + lr;
      af[m][s] = *(const short8*)(myh + (((row*64) + s*16 + lg*4) ^ ((row & 7) << 2)));
    }

  const char* wbase = (const char*)wlds;
  f32x4 acc[2][4];
  #pragma unroll
  for (int m = 0; m < 2; ++m)
    #pragma unroll
    for (int np = 0; np < 4; ++np) acc[m][np] = (f32x4){0.f,0.f,0.f,0.f};

  #pragma unroll
  for (int np = 0; np < 4; ++np) {
    int col = np*16 + lr;
    #pragma unroll
    for (int s = 0; s < 4; ++s) {
      short8 bh = *(const short8*)(wbase + ((col*256 + s*64 + lg*16) ^ sx));
      #pragma unroll
      for (int m = 0; m < 2; ++m)
        acc[m][np] = __builtin_amdgcn_mfma_f32_16x16x32_bf16(af[m][s], bh, acc[m][np], 0, 0, 0);
    }
  }

  #pragma unroll
  for (int np = 0; np < 4; ++np) {
    int col = np*16 + lr;
    bool act = col < 50;
    float bias = act ? pb[col] : 0.f;
    #pragma unroll
    for (int m = 0; m < 2; ++m)
      #pragma unroll
      for (int r = 0; r < 4; ++r) {
        float v = acc[m][np][r] + bias;
        float sp = fmaxf(v, 0.f) + log1pf(__expf(-fabsf(v)));
        if (act) out[(rowbase + m*16 + lg*4 + r)*50 + col] = sp;
      }
  }
}

extern "C" void kernel_launch(void* const* d_in, const int* in_sizes, int n_in,
                              void* d_out, int out_size, void* d_ws, size_t ws_size,
                              hipStream_t stream) {
  const float* x    = (const float*)d_in[0];
  const float* ew   = (const float*)d_in[1];
  const float* eb   = (const float*)d_in[2];
  const float* ln0g = (const float*)d_in[3];
  const float* ln0b = (const float*)d_in[4];
  const float* pw   = (const float*)d_in[5];
  const float* pb   = (const float*)d_in[6];
  float* out = (float*)d_out;

  size_t nBT  = (size_t)BB*TT*HH;
  size_t nSum = (size_t)BB*NC*HH;
  unsigned short* h  = (unsigned short*)d_ws;
  unsigned*       ab = (unsigned*)(h + nBT);
  float* AsT  = (float*)(ab + nBT);
  float* BsT  = AsT + nSum;
  float* carT = BsT + nSum;
  unsigned short* wt   = (unsigned short*)(carT + nSum);
  unsigned short* wt_e = wt + 3*32768;
  unsigned short* wt_p = wt_e + 8192;

  prep_kernel<<<448, 256, 0, stream>>>((const float*)d_in[7], (const float*)d_in[11],
                                       (const float*)d_in[15], ew, pw, wt, wt_e, wt_p);
  embed_mfma_kernel<<<(BB*TT)/128, 256, 0, stream>>>(x, wt_e, eb, ln0g, ln0b, h);

  for (int l = 0; l < 3; ++l) {
    const float* gb = (const float*)d_in[8 + 4*l];
    const float* lg = (const float*)d_in[9 + 4*l];
    const float* lb = (const float*)d_in[10 + 4*l];
    gru_mm_kernel<<<(BB*NC)/4, 256, 0, stream>>>(h, wt + (size_t)l*32768, gb, ab, AsT, BsT);
    scan2_kernel<<<256, 256, 0, stream>>>(AsT, BsT, carT);
    if (l < 2) {
      apply_kernel<<<(BB*NC)/8, 256, 0, stream>>>(ab, carT, lg, lb, h);
    } else {
      apply_proj_kernel<<<(BB*NC)/4, 256, 0, stream>>>(ab, carT, lg, lb, wt_p, pb, out);
    }
  }
}